// Round 1
// baseline (2256.200 us; speedup 1.0000x reference)
//
#include <hip/hip_runtime.h>
#include <math.h>

#define NN 100000
#define NE 3200000
#define FIN 128
#define HD 256
#define CO 47

// ---------------- CSR build ----------------

__global__ void count_deg_kernel(const int* __restrict__ dst, int* __restrict__ cnt) {
    int stride = gridDim.x * blockDim.x;
    for (int e = blockIdx.x * blockDim.x + threadIdx.x; e < NE; e += stride)
        atomicAdd(&cnt[dst[e]], 1);
}

__global__ void dinv_kernel(const int* __restrict__ cnt, float* __restrict__ dinv) {
    int i = blockIdx.x * blockDim.x + threadIdx.x;
    if (i < NN) dinv[i] = rsqrtf((float)cnt[i] + 1.0f);   // +1 self loop
}

// single-block exclusive scan over NN counts -> offs[0..NN]
__global__ void scan_kernel(const int* __restrict__ cnt, int* __restrict__ offs) {
    __shared__ int tmp[1024];
    __shared__ int carry;
    if (threadIdx.x == 0) carry = 0;
    __syncthreads();
    for (int base = 0; base < NN; base += 1024) {
        int i = base + threadIdx.x;
        int v = (i < NN) ? cnt[i] : 0;
        tmp[threadIdx.x] = v;
        __syncthreads();
        for (int off = 1; off < 1024; off <<= 1) {
            int t = (threadIdx.x >= off) ? tmp[threadIdx.x - off] : 0;
            __syncthreads();
            tmp[threadIdx.x] += t;
            __syncthreads();
        }
        int incl = tmp[threadIdx.x];
        int c = carry;
        if (i < NN) offs[i] = c + incl - v;   // exclusive
        __syncthreads();
        if (threadIdx.x == 1023) carry = c + tmp[1023];
        __syncthreads();
    }
    if (threadIdx.x == 0) offs[NN] = carry;
}

__global__ void fill_csr_kernel(const int* __restrict__ src, const int* __restrict__ dst,
                                const int* __restrict__ offs, int* __restrict__ cur,
                                int* __restrict__ csr) {
    int stride = gridDim.x * blockDim.x;
    for (int e = blockIdx.x * blockDim.x + threadIdx.x; e < NE; e += stride) {
        int d = dst[e];
        int p = offs[d] + atomicAdd(&cur[d], 1);
        csr[p] = src[e];
    }
}

// ---------------- GEMM (fp32 vector ALU), optional BN+ReLU on A-load, dinv epilogue ----

template<int K, bool XFORM>
__global__ __launch_bounds__(256) void gemm_kernel(
    const float* __restrict__ A, int lda,
    const float* __restrict__ B, int ldb, int ncols,
    const float* __restrict__ ss,       // [K] scale, [K] shift (XFORM only)
    const float* __restrict__ dinv,
    float* __restrict__ out, int ldo)
{
    __shared__ __align__(16) float As[64][33];
    __shared__ __align__(16) float Bs[32][64];
    const int row0 = blockIdx.x * 64;
    const int col0 = blockIdx.y * 64;
    const int tid = threadIdx.x;
    const int tx = tid & 15, ty = tid >> 4;
    float acc[4][4] = {};
    for (int k0 = 0; k0 < K; k0 += 32) {
        #pragma unroll
        for (int i = 0; i < 8; ++i) {
            int idx = tid + i * 256;
            int m = idx >> 5, kk = idx & 31;
            int r = row0 + m;
            float a = (r < NN) ? A[(size_t)r * lda + k0 + kk] : 0.0f;
            if (XFORM) a = fmaxf(fmaf(a, ss[k0 + kk], ss[K + k0 + kk]), 0.0f);
            As[m][kk] = a;
        }
        #pragma unroll
        for (int i = 0; i < 8; ++i) {
            int idx = tid + i * 256;
            int kk = idx >> 6, c = idx & 63;
            int cc = col0 + c;
            Bs[kk][c] = (cc < ncols) ? B[(size_t)(k0 + kk) * ldb + cc] : 0.0f;
        }
        __syncthreads();
        #pragma unroll
        for (int kk = 0; kk < 32; ++kk) {
            float a0 = As[ty * 4 + 0][kk];
            float a1 = As[ty * 4 + 1][kk];
            float a2 = As[ty * 4 + 2][kk];
            float a3 = As[ty * 4 + 3][kk];
            float4 b4 = *(const float4*)&Bs[kk][tx * 4];
            acc[0][0] = fmaf(a0, b4.x, acc[0][0]); acc[0][1] = fmaf(a0, b4.y, acc[0][1]);
            acc[0][2] = fmaf(a0, b4.z, acc[0][2]); acc[0][3] = fmaf(a0, b4.w, acc[0][3]);
            acc[1][0] = fmaf(a1, b4.x, acc[1][0]); acc[1][1] = fmaf(a1, b4.y, acc[1][1]);
            acc[1][2] = fmaf(a1, b4.z, acc[1][2]); acc[1][3] = fmaf(a1, b4.w, acc[1][3]);
            acc[2][0] = fmaf(a2, b4.x, acc[2][0]); acc[2][1] = fmaf(a2, b4.y, acc[2][1]);
            acc[2][2] = fmaf(a2, b4.z, acc[2][2]); acc[2][3] = fmaf(a2, b4.w, acc[2][3]);
            acc[3][0] = fmaf(a3, b4.x, acc[3][0]); acc[3][1] = fmaf(a3, b4.y, acc[3][1]);
            acc[3][2] = fmaf(a3, b4.z, acc[3][2]); acc[3][3] = fmaf(a3, b4.w, acc[3][3]);
        }
        __syncthreads();
    }
    #pragma unroll
    for (int i = 0; i < 4; ++i) {
        int r = row0 + ty * 4 + i;
        if (r >= NN) continue;
        float dv = dinv[r];
        #pragma unroll
        for (int j = 0; j < 4; ++j) {
            int c = col0 + tx * 4 + j;
            if (c < ncols) out[(size_t)r * ldo + c] = acc[i][j] * dv;
        }
    }
}

// ---------------- aggregation: wave per node, atomic-free ----------------

__global__ __launch_bounds__(256) void aggregate256_kernel(
    const float* __restrict__ hp, const int* __restrict__ offs,
    const int* __restrict__ csr, const float* __restrict__ dinv,
    const float* __restrict__ bias, float* __restrict__ out)
{
    int lane = threadIdx.x & 63;
    int v = blockIdx.x * 4 + (threadIdx.x >> 6);
    float4 acc = ((const float4*)(hp + (size_t)v * HD))[lane];  // self loop
    int b = offs[v], e = offs[v + 1];
    int j = b;
    for (; j + 4 <= e; j += 4) {
        int s0 = csr[j], s1 = csr[j + 1], s2 = csr[j + 2], s3 = csr[j + 3];
        float4 t0 = ((const float4*)(hp + (size_t)s0 * HD))[lane];
        float4 t1 = ((const float4*)(hp + (size_t)s1 * HD))[lane];
        float4 t2 = ((const float4*)(hp + (size_t)s2 * HD))[lane];
        float4 t3 = ((const float4*)(hp + (size_t)s3 * HD))[lane];
        acc.x += t0.x + t1.x + t2.x + t3.x;
        acc.y += t0.y + t1.y + t2.y + t3.y;
        acc.z += t0.z + t1.z + t2.z + t3.z;
        acc.w += t0.w + t1.w + t2.w + t3.w;
    }
    for (; j < e; ++j) {
        int s = csr[j];
        float4 t = ((const float4*)(hp + (size_t)s * HD))[lane];
        acc.x += t.x; acc.y += t.y; acc.z += t.z; acc.w += t.w;
    }
    float dv = dinv[v];
    float4 bb = ((const float4*)bias)[lane];
    float4 o;
    o.x = fmaf(acc.x, dv, bb.x);
    o.y = fmaf(acc.y, dv, bb.y);
    o.z = fmaf(acc.z, dv, bb.z);
    o.w = fmaf(acc.w, dv, bb.w);
    ((float4*)(out + (size_t)v * HD))[lane] = o;
}

__global__ __launch_bounds__(256) void aggregate47_lsm_kernel(
    const float* __restrict__ hp, const int* __restrict__ offs,
    const int* __restrict__ csr, const float* __restrict__ dinv,
    const float* __restrict__ bias, float* __restrict__ out)
{
    int lane = threadIdx.x & 63;
    int v = blockIdx.x * 4 + (threadIdx.x >> 6);
    bool act = lane < CO;
    float acc = act ? hp[(size_t)v * CO + lane] : 0.0f;
    int b = offs[v], e = offs[v + 1];
    int j = b;
    for (; j + 4 <= e; j += 4) {
        int s0 = csr[j], s1 = csr[j + 1], s2 = csr[j + 2], s3 = csr[j + 3];
        if (act) {
            acc += hp[(size_t)s0 * CO + lane];
            acc += hp[(size_t)s1 * CO + lane];
            acc += hp[(size_t)s2 * CO + lane];
            acc += hp[(size_t)s3 * CO + lane];
        }
    }
    for (; j < e; ++j) {
        int s = csr[j];
        if (act) acc += hp[(size_t)s * CO + lane];
    }
    float val = act ? fmaf(acc, dinv[v], bias[lane]) : -1e30f;
    float m = val;
    #pragma unroll
    for (int o = 32; o > 0; o >>= 1) m = fmaxf(m, __shfl_xor(m, o, 64));
    float ex = act ? expf(val - m) : 0.0f;
    float sum = ex;
    #pragma unroll
    for (int o = 32; o > 0; o >>= 1) sum += __shfl_xor(sum, o, 64);
    if (act) out[(size_t)v * CO + lane] = val - m - logf(sum);
}

// ---------------- BatchNorm stats ----------------

__global__ void bn_stats_kernel(const float* __restrict__ h, float* __restrict__ sums) {
    int t = threadIdx.x;   // 256 = one feature each
    float s1 = 0.0f, s2 = 0.0f;
    for (int r = blockIdx.x; r < NN; r += gridDim.x) {
        float v = h[(size_t)r * HD + t];
        s1 += v; s2 += v * v;
    }
    atomicAdd(&sums[t], s1);
    atomicAdd(&sums[HD + t], s2);
}

__global__ void bn_finalize_kernel(const float* __restrict__ sums,
                                   const float* __restrict__ g, const float* __restrict__ be,
                                   float* __restrict__ ss) {
    int t = threadIdx.x;
    float mean = sums[t] * (1.0f / NN);
    float var = sums[HD + t] * (1.0f / NN) - mean * mean;
    float sc = g[t] * rsqrtf(var + 1e-5f);
    ss[t] = sc;
    ss[HD + t] = be[t] - mean * sc;
}

// ---------------- launch ----------------

extern "C" void kernel_launch(void* const* d_in, const int* in_sizes, int n_in,
                              void* d_out, int out_size, void* d_ws, size_t ws_size,
                              hipStream_t stream) {
    const float* x   = (const float*)d_in[0];
    const int*   ei  = (const int*)d_in[1];
    const float* W0  = (const float*)d_in[3];
    const float* b0  = (const float*)d_in[4];
    const float* g0  = (const float*)d_in[5];
    const float* be0 = (const float*)d_in[6];
    const float* W1  = (const float*)d_in[7];
    const float* b1  = (const float*)d_in[8];
    const float* g1  = (const float*)d_in[9];
    const float* be1 = (const float*)d_in[10];
    const float* W2  = (const float*)d_in[11];
    const float* b2  = (const float*)d_in[12];
    float* out = (float*)d_out;

    const int* src = ei;            // edge_index[0]
    const int* dst = ei + NE;       // edge_index[1]

    char* ws = (char*)d_ws;
    float* bufA = (float*)(ws);                         // 102,400,000 B
    float* bufB = (float*)(ws + 102400000);             // 102,400,000 B
    int*   csr  = (int*)  (ws + 204800000);             // 12,800,000 B
    int*   offs = (int*)  (ws + 217600000);             // 400,016 B
    int*   cur  = (int*)  (ws + 218000016);             // 400,000 B
    float* dinv = (float*)(ws + 218400016);             // 400,000 B
    float* bns  = (float*)(ws + 218800016);             // 2048 B
    float* ss   = (float*)(ws + 218802064);             // 2048 B

    // CSR build (reused by all 3 layers)
    hipMemsetAsync(cur, 0, NN * sizeof(int), stream);
    count_deg_kernel<<<2048, 256, 0, stream>>>(dst, cur);
    dinv_kernel<<<(NN + 255) / 256, 256, 0, stream>>>(cur, dinv);
    scan_kernel<<<1, 1024, 0, stream>>>(cur, offs);
    hipMemsetAsync(cur, 0, NN * sizeof(int), stream);
    fill_csr_kernel<<<2048, 256, 0, stream>>>(src, dst, offs, cur, csr);

    const int MBLK = (NN + 63) / 64;   // 1563

    // Layer 0: h' = dinv * (x @ W0); agg -> bufB (+b0)
    gemm_kernel<FIN, false><<<dim3(MBLK, 4), 256, 0, stream>>>(
        x, FIN, W0, HD, HD, nullptr, dinv, bufA, HD);
    aggregate256_kernel<<<NN / 4, 256, 0, stream>>>(bufA, offs, csr, dinv, b0, bufB);

    hipMemsetAsync(bns, 0, 2 * HD * sizeof(float), stream);
    bn_stats_kernel<<<1024, 256, 0, stream>>>(bufB, bns);
    bn_finalize_kernel<<<1, HD, 0, stream>>>(bns, g0, be0, ss);

    // Layer 1: A = relu(bn(bufB)) fused on load
    gemm_kernel<HD, true><<<dim3(MBLK, 4), 256, 0, stream>>>(
        bufB, HD, W1, HD, HD, ss, dinv, bufA, HD);
    aggregate256_kernel<<<NN / 4, 256, 0, stream>>>(bufA, offs, csr, dinv, b1, bufB);

    hipMemsetAsync(bns, 0, 2 * HD * sizeof(float), stream);
    bn_stats_kernel<<<1024, 256, 0, stream>>>(bufB, bns);
    bn_finalize_kernel<<<1, HD, 0, stream>>>(bns, g1, be1, ss);

    // Layer 2: -> [N,47], agg + log_softmax to d_out
    gemm_kernel<HD, true><<<dim3(MBLK, 1), 256, 0, stream>>>(
        bufB, HD, W2, CO, CO, ss, dinv, bufA, CO);
    aggregate47_lsm_kernel<<<NN / 4, 256, 0, stream>>>(bufA, offs, csr, dinv, b2, out);
}

// Round 2
// 1407.297 us; speedup vs baseline: 1.6032x; 1.6032x over previous
//
#include <hip/hip_runtime.h>
#include <math.h>

#define NN 100000
#define NE 3200000
#define FIN 128
#define HD 256
#define CO 47
#define COP 64   // padded row for layer-2 gather (one 128B line)

typedef _Float16 h2 __attribute__((ext_vector_type(2)));
typedef _Float16 h4 __attribute__((ext_vector_type(4)));
typedef _Float16 h8 __attribute__((ext_vector_type(8)));

// ---------------- CSR build ----------------

__global__ void count_deg_kernel(const int* __restrict__ dst, int* __restrict__ cnt) {
    int stride = gridDim.x * blockDim.x;
    for (int e = blockIdx.x * blockDim.x + threadIdx.x; e < NE; e += stride)
        atomicAdd(&cnt[dst[e]], 1);
}

__global__ void dinv_kernel(const int* __restrict__ cnt, float* __restrict__ dinv) {
    int i = blockIdx.x * blockDim.x + threadIdx.x;
    if (i < NN) dinv[i] = rsqrtf((float)cnt[i] + 1.0f);   // +1 self loop
}

__global__ void scan_kernel(const int* __restrict__ cnt, int* __restrict__ offs) {
    __shared__ int tmp[1024];
    __shared__ int carry;
    if (threadIdx.x == 0) carry = 0;
    __syncthreads();
    for (int base = 0; base < NN; base += 1024) {
        int i = base + threadIdx.x;
        int v = (i < NN) ? cnt[i] : 0;
        tmp[threadIdx.x] = v;
        __syncthreads();
        for (int off = 1; off < 1024; off <<= 1) {
            int t = (threadIdx.x >= off) ? tmp[threadIdx.x - off] : 0;
            __syncthreads();
            tmp[threadIdx.x] += t;
            __syncthreads();
        }
        int incl = tmp[threadIdx.x];
        int c = carry;
        if (i < NN) offs[i] = c + incl - v;   // exclusive
        __syncthreads();
        if (threadIdx.x == 1023) carry = c + tmp[1023];
        __syncthreads();
    }
    if (threadIdx.x == 0) offs[NN] = carry;
}

__global__ void fill_csr_kernel(const int* __restrict__ src, const int* __restrict__ dst,
                                const int* __restrict__ offs, int* __restrict__ cur,
                                int* __restrict__ csr) {
    int stride = gridDim.x * blockDim.x;
    for (int e = blockIdx.x * blockDim.x + threadIdx.x; e < NE; e += stride) {
        int d = dst[e];
        int p = offs[d] + atomicAdd(&cur[d], 1);
        csr[p] = src[e];
    }
}

// ---------------- x -> fp16, pre-scaled by dinv ----------------

__global__ void conv_x_kernel(const float* __restrict__ x, const float* __restrict__ dinv,
                              _Float16* __restrict__ xh) {
    int i = blockIdx.x * 256 + threadIdx.x;     // over NN*FIN/4 float4s
    if (i >= NN * FIN / 4) return;
    int r = i >> 5;                             // /(FIN/4)
    float4 v = ((const float4*)x)[i];
    float dv = dinv[r];
    h4 o; o[0] = (_Float16)(v.x * dv); o[1] = (_Float16)(v.y * dv);
    o[2] = (_Float16)(v.z * dv); o[3] = (_Float16)(v.w * dv);
    ((h4*)xh)[i] = o;
}

// ---------------- aggregation (wave per node, atomic-free, fp16 rows) ----------------

__global__ __launch_bounds__(256) void agg128_kernel(
    const _Float16* __restrict__ xh, const int* __restrict__ offs,
    const int* __restrict__ csr, const float* __restrict__ dinv,
    _Float16* __restrict__ out)
{
    int lane = threadIdx.x & 63;
    int v = blockIdx.x * 4 + (threadIdx.x >> 6);
    const h2* rows = (const h2*)xh;             // 64 h2 per row
    h2 sv = rows[(size_t)v * 64 + lane];
    float ax = (float)sv[0], ay = (float)sv[1];
    int b = offs[v], e = offs[v + 1], j = b;
    for (; j + 8 <= e; j += 8) {
        int s[8];
        #pragma unroll
        for (int q = 0; q < 8; ++q) s[q] = csr[j + q];
        #pragma unroll
        for (int q = 0; q < 8; ++q) {
            h2 t = rows[(size_t)s[q] * 64 + lane];
            ax += (float)t[0]; ay += (float)t[1];
        }
    }
    for (; j < e; ++j) {
        h2 t = rows[(size_t)csr[j] * 64 + lane];
        ax += (float)t[0]; ay += (float)t[1];
    }
    float dv = dinv[v];
    h2 o; o[0] = (_Float16)(ax * dv); o[1] = (_Float16)(ay * dv);
    ((h2*)out)[(size_t)v * 64 + lane] = o;
}

__global__ __launch_bounds__(256) void agg256_kernel(
    const _Float16* __restrict__ hp, const int* __restrict__ offs,
    const int* __restrict__ csr, const float* __restrict__ dinv,
    _Float16* __restrict__ out)
{
    int lane = threadIdx.x & 63;
    int v = blockIdx.x * 4 + (threadIdx.x >> 6);
    const h4* rows = (const h4*)hp;             // 64 h4 per row
    h4 sv = rows[(size_t)v * 64 + lane];
    float a0 = (float)sv[0], a1 = (float)sv[1], a2 = (float)sv[2], a3 = (float)sv[3];
    int b = offs[v], e = offs[v + 1], j = b;
    for (; j + 8 <= e; j += 8) {
        int s[8];
        #pragma unroll
        for (int q = 0; q < 8; ++q) s[q] = csr[j + q];
        #pragma unroll
        for (int q = 0; q < 8; ++q) {
            h4 t = rows[(size_t)s[q] * 64 + lane];
            a0 += (float)t[0]; a1 += (float)t[1]; a2 += (float)t[2]; a3 += (float)t[3];
        }
    }
    for (; j < e; ++j) {
        h4 t = rows[(size_t)csr[j] * 64 + lane];
        a0 += (float)t[0]; a1 += (float)t[1]; a2 += (float)t[2]; a3 += (float)t[3];
    }
    float dv = dinv[v];
    h4 o; o[0] = (_Float16)(a0 * dv); o[1] = (_Float16)(a1 * dv);
    o[2] = (_Float16)(a2 * dv); o[3] = (_Float16)(a3 * dv);
    ((h4*)out)[(size_t)v * 64 + lane] = o;
}

__global__ __launch_bounds__(256) void agg47_lsm_kernel(
    const _Float16* __restrict__ t2, const int* __restrict__ offs,
    const int* __restrict__ csr, const float* __restrict__ dinv,
    const float* __restrict__ bias, float* __restrict__ out)
{
    int lane = threadIdx.x & 63;
    int v = blockIdx.x * 4 + (threadIdx.x >> 6);
    float acc = (float)t2[(size_t)v * COP + lane];     // padded cols read 0
    int b = offs[v], e = offs[v + 1], j = b;
    for (; j + 8 <= e; j += 8) {
        int s[8];
        #pragma unroll
        for (int q = 0; q < 8; ++q) s[q] = csr[j + q];
        #pragma unroll
        for (int q = 0; q < 8; ++q) acc += (float)t2[(size_t)s[q] * COP + lane];
    }
    for (; j < e; ++j) acc += (float)t2[(size_t)csr[j] * COP + lane];
    bool act = lane < CO;
    float val = act ? fmaf(acc, dinv[v], bias[lane]) : -1e30f;
    float m = val;
    #pragma unroll
    for (int o = 32; o > 0; o >>= 1) m = fmaxf(m, __shfl_xor(m, o, 64));
    float ex = act ? expf(val - m) : 0.0f;
    float sum = ex;
    #pragma unroll
    for (int o = 32; o > 0; o >>= 1) sum += __shfl_xor(sum, o, 64);
    if (act) out[(size_t)v * CO + lane] = val - m - logf(sum);
}

// ---------------- GEMM: fp16 A (BN+ReLU fused on load), fp32 B/compute, fp16 out ----

template<int K, bool XFORM, bool EPI_DINV>
__global__ __launch_bounds__(256) void gemm_kernel(
    const _Float16* __restrict__ A, int lda,
    const float* __restrict__ B, int ldb, int ncolsB,
    const float* __restrict__ ss, const float* __restrict__ dinv,
    _Float16* __restrict__ out, int ldo, int ncolsO)
{
    __shared__ __align__(16) float As[64][33];
    __shared__ __align__(16) float Bs[32][64];
    __shared__ float SS[2 * K];
    const int row0 = blockIdx.x * 64;
    const int col0 = blockIdx.y * 64;
    const int tid = threadIdx.x;
    const int tx = tid & 15, ty = tid >> 4;
    if (XFORM) {
        for (int i = tid; i < 2 * K; i += 256) SS[i] = ss[i];
        __syncthreads();
    }
    float acc[4][4] = {};
    for (int k0 = 0; k0 < K; k0 += 32) {
        {
            int idx = tid * 8;
            int m = idx >> 5, kk = idx & 31;
            int r = row0 + m;
            h8 av = {};
            if (r < NN) av = *(const h8*)&A[(size_t)r * lda + k0 + kk];
            #pragma unroll
            for (int j = 0; j < 8; ++j) {
                float a = (float)av[j];
                if (XFORM) a = fmaxf(fmaf(a, SS[k0 + kk + j], SS[K + k0 + kk + j]), 0.0f);
                As[m][kk + j] = a;
            }
        }
        #pragma unroll
        for (int i = 0; i < 8; ++i) {
            int idx = tid + i * 256;
            int kk = idx >> 6, c = idx & 63;
            int cc = col0 + c;
            Bs[kk][c] = (cc < ncolsB) ? B[(size_t)(k0 + kk) * ldb + cc] : 0.0f;
        }
        __syncthreads();
        #pragma unroll
        for (int kk = 0; kk < 32; ++kk) {
            float a0 = As[ty * 4 + 0][kk];
            float a1 = As[ty * 4 + 1][kk];
            float a2 = As[ty * 4 + 2][kk];
            float a3 = As[ty * 4 + 3][kk];
            float4 b4 = *(const float4*)&Bs[kk][tx * 4];
            acc[0][0] = fmaf(a0, b4.x, acc[0][0]); acc[0][1] = fmaf(a0, b4.y, acc[0][1]);
            acc[0][2] = fmaf(a0, b4.z, acc[0][2]); acc[0][3] = fmaf(a0, b4.w, acc[0][3]);
            acc[1][0] = fmaf(a1, b4.x, acc[1][0]); acc[1][1] = fmaf(a1, b4.y, acc[1][1]);
            acc[1][2] = fmaf(a1, b4.z, acc[1][2]); acc[1][3] = fmaf(a1, b4.w, acc[1][3]);
            acc[2][0] = fmaf(a2, b4.x, acc[2][0]); acc[2][1] = fmaf(a2, b4.y, acc[2][1]);
            acc[2][2] = fmaf(a2, b4.z, acc[2][2]); acc[2][3] = fmaf(a2, b4.w, acc[2][3]);
            acc[3][0] = fmaf(a3, b4.x, acc[3][0]); acc[3][1] = fmaf(a3, b4.y, acc[3][1]);
            acc[3][2] = fmaf(a3, b4.z, acc[3][2]); acc[3][3] = fmaf(a3, b4.w, acc[3][3]);
        }
        __syncthreads();
    }
    #pragma unroll
    for (int i = 0; i < 4; ++i) {
        int r = row0 + ty * 4 + i;
        if (r >= NN) continue;
        float dv = EPI_DINV ? dinv[r] : 1.0f;
        #pragma unroll
        for (int j = 0; j < 4; ++j) {
            int c = col0 + tx * 4 + j;
            if (c < ncolsO) out[(size_t)r * ldo + c] = (_Float16)(acc[i][j] * dv);
        }
    }
}

// ---------------- BatchNorm stats (fp16 input, fp32 accumulate) ----------------

__global__ void bn_stats_kernel(const _Float16* __restrict__ h, float* __restrict__ sums) {
    int t = threadIdx.x;
    float s1 = 0.0f, s2 = 0.0f;
    for (int r = blockIdx.x; r < NN; r += gridDim.x) {
        float v = (float)h[(size_t)r * HD + t];
        s1 += v; s2 += v * v;
    }
    atomicAdd(&sums[t], s1);
    atomicAdd(&sums[HD + t], s2);
}

__global__ void bn_finalize_kernel(const float* __restrict__ sums,
                                   const float* __restrict__ g, const float* __restrict__ be,
                                   float* __restrict__ ss) {
    int t = threadIdx.x;
    float mean = sums[t] * (1.0f / NN);
    float var = sums[HD + t] * (1.0f / NN) - mean * mean;
    float sc = g[t] * rsqrtf(var + 1e-5f);
    ss[t] = sc;
    ss[HD + t] = be[t] - mean * sc;
}

// ---------------- launch ----------------

extern "C" void kernel_launch(void* const* d_in, const int* in_sizes, int n_in,
                              void* d_out, int out_size, void* d_ws, size_t ws_size,
                              hipStream_t stream) {
    const float* x   = (const float*)d_in[0];
    const int*   ei  = (const int*)d_in[1];
    const float* W0  = (const float*)d_in[3];
    const float* g0  = (const float*)d_in[5];
    const float* be0 = (const float*)d_in[6];
    const float* W1  = (const float*)d_in[7];
    const float* g1  = (const float*)d_in[9];
    const float* be1 = (const float*)d_in[10];
    const float* W2  = (const float*)d_in[11];
    const float* b2  = (const float*)d_in[12];
    float* out = (float*)d_out;

    const int* src = ei;            // edge_index[0]
    const int* dst = ei + NE;       // edge_index[1]

    // workspace layout (b0/b1 cancel under BatchNorm; only b2 survives)
    const size_t S = 51200000;                       // 100000*256*2 bytes
    char* ws = (char*)d_ws;
    _Float16* S1   = (_Float16*)ws;                  // t1 / t2 slot
    _Float16* xh   = S1;                             // [NN][128] fp16 (25.6MB)
    _Float16* a0   = S1 + 12800000;                  // [NN][128] fp16 (25.6MB)
    _Float16* S2   = (_Float16*)(ws + S);            // h0 / h1 slot
    int*   csr  = (int*)  (ws + 2 * S);              // 12.8MB
    int*   offs = (int*)  (ws + 2 * S + 12800000);   // 400,004B -> pad 400,064
    int*   cur  = (int*)  (ws + 2 * S + 13200064);
    float* dinv = (float*)(ws + 2 * S + 13600064);
    float* bns  = (float*)(ws + 2 * S + 14000064);
    float* ss   = (float*)(ws + 2 * S + 14002112);

    // CSR build (reused by all 3 layers)
    hipMemsetAsync(cur, 0, NN * sizeof(int), stream);
    count_deg_kernel<<<2048, 256, 0, stream>>>(dst, cur);
    dinv_kernel<<<(NN + 255) / 256, 256, 0, stream>>>(cur, dinv);
    scan_kernel<<<1, 1024, 0, stream>>>(cur, offs);
    hipMemsetAsync(cur, 0, NN * sizeof(int), stream);
    fill_csr_kernel<<<2048, 256, 0, stream>>>(src, dst, offs, cur, csr);

    const int MBLK = (NN + 63) / 64;   // 1563

    // Layer 0 (reassociated): agg0 = D^-1/2 (A+I) D^-1/2 x  (128-wide), then GEMM
    conv_x_kernel<<<(NN * FIN / 4 + 255) / 256, 256, 0, stream>>>(x, dinv, xh);
    agg128_kernel<<<NN / 4, 256, 0, stream>>>(xh, offs, csr, dinv, a0);
    gemm_kernel<FIN, false, false><<<dim3(MBLK, 4), 256, 0, stream>>>(
        a0, FIN, W0, HD, HD, nullptr, dinv, S2, HD, HD);          // h0 -> S2

    hipMemsetAsync(bns, 0, 2 * HD * sizeof(float), stream);
    bn_stats_kernel<<<1024, 256, 0, stream>>>(S2, bns);
    bn_finalize_kernel<<<1, HD, 0, stream>>>(bns, g0, be0, ss);

    // Layer 1: t1 = dinv * (relu(bn(h0)) @ W1); h1 = dinv*(A+I)t1
    gemm_kernel<HD, true, true><<<dim3(MBLK, 4), 256, 0, stream>>>(
        S2, HD, W1, HD, HD, ss, dinv, S1, HD, HD);                // t1 -> S1
    agg256_kernel<<<NN / 4, 256, 0, stream>>>(S1, offs, csr, dinv, S2);  // h1 -> S2

    hipMemsetAsync(bns, 0, 2 * HD * sizeof(float), stream);
    bn_stats_kernel<<<1024, 256, 0, stream>>>(S2, bns);
    bn_finalize_kernel<<<1, HD, 0, stream>>>(bns, g1, be1, ss);

    // Layer 2: t2 = dinv * (relu(bn(h1)) @ W2), rows padded to 64; agg + log_softmax
    gemm_kernel<HD, true, true><<<dim3(MBLK, 1), 256, 0, stream>>>(
        S2, HD, W2, CO, CO, ss, dinv, S1, COP, COP);              // t2 -> S1
    agg47_lsm_kernel<<<NN / 4, 256, 0, stream>>>(S1, offs, csr, dinv, b2, out);
}

// Round 3
// 1079.505 us; speedup vs baseline: 2.0900x; 1.3036x over previous
//
#include <hip/hip_runtime.h>
#include <math.h>

#define NN 100000
#define NE 3200000
#define FIN 128
#define HD 256
#define CO 47
#define COP 64   // padded row for layer-2 gather (one 128B line)

typedef _Float16 h2 __attribute__((ext_vector_type(2)));
typedef _Float16 h4 __attribute__((ext_vector_type(4)));
typedef _Float16 h8 __attribute__((ext_vector_type(8)));
typedef float f32x4 __attribute__((ext_vector_type(4)));

// ---------------- CSR build ----------------

__global__ void count_deg_kernel(const int* __restrict__ dst, int* __restrict__ cnt) {
    int e = blockIdx.x * 256 + threadIdx.x;
    if (e < NE) atomicAdd(&cnt[dst[e]], 1);
}

__global__ void dinv_kernel(const int* __restrict__ cnt, float* __restrict__ dinv) {
    int i = blockIdx.x * 256 + threadIdx.x;
    if (i < NN) dinv[i] = rsqrtf((float)cnt[i] + 1.0f);   // +1 self loop
}

// hierarchical exclusive scan: cnt[NN] -> offs[NN+1]
__global__ void scan1_kernel(const int* __restrict__ cnt, int* __restrict__ offs,
                             int* __restrict__ bsum) {
    __shared__ int tmp[256];
    int t = threadIdx.x;
    int i = blockIdx.x * 256 + t;
    int v = (i < NN) ? cnt[i] : 0;
    tmp[t] = v;
    __syncthreads();
    #pragma unroll
    for (int off = 1; off < 256; off <<= 1) {
        int u = (t >= off) ? tmp[t - off] : 0;
        __syncthreads();
        tmp[t] += u;
        __syncthreads();
    }
    if (i < NN) offs[i] = tmp[t] - v;          // exclusive within block
    if (t == 255) bsum[blockIdx.x] = tmp[255];
}

__global__ void scan2_kernel(int* __restrict__ bsum, int nb) {
    __shared__ int tmp[512];
    int t = threadIdx.x;
    int v = (t < nb) ? bsum[t] : 0;
    tmp[t] = v;
    __syncthreads();
    #pragma unroll
    for (int off = 1; off < 512; off <<= 1) {
        int u = (t >= off) ? tmp[t - off] : 0;
        __syncthreads();
        tmp[t] += u;
        __syncthreads();
    }
    if (t < nb) bsum[t] = tmp[t] - v;          // exclusive
    if (t == nb - 1) bsum[nb] = tmp[t];        // total
}

__global__ void scan3_kernel(int* __restrict__ offs, const int* __restrict__ bsum, int nb) {
    int i = blockIdx.x * 256 + threadIdx.x;
    if (i < NN) offs[i] += bsum[i >> 8];
    if (i == 0) offs[NN] = bsum[nb];
}

__global__ void fill_csr_kernel(const int* __restrict__ src, const int* __restrict__ dst,
                                int* __restrict__ cur, int* __restrict__ csr) {
    int e = blockIdx.x * 256 + threadIdx.x;
    if (e >= NE) return;
    int p = atomicAdd(&cur[dst[e]], 1);
    csr[p] = src[e];
}

// ---------------- weight convert: Wt[n][k] = (fp16) W[k][n], rows >= N zeroed ----

template<int K>
__global__ void wtrans_kernel(const float* __restrict__ W, _Float16* __restrict__ Wt,
                              int N, int NP) {
    int i = blockIdx.x * 256 + threadIdx.x;
    if (i >= NP * K) return;
    int n = i / K, k = i % K;
    float v = (n < N) ? W[(size_t)k * N + n] : 0.0f;
    Wt[i] = (_Float16)v;
}

// ---------------- x -> fp16, pre-scaled by dinv ----------------

__global__ void conv_x_kernel(const float* __restrict__ x, const float* __restrict__ dinv,
                              _Float16* __restrict__ xh) {
    int i = blockIdx.x * 256 + threadIdx.x;     // over NN*FIN/4 float4s
    if (i >= NN * FIN / 4) return;
    int r = i >> 5;                             // /(FIN/4)
    float4 v = ((const float4*)x)[i];
    float dv = dinv[r];
    h4 o; o[0] = (_Float16)(v.x * dv); o[1] = (_Float16)(v.y * dv);
    o[2] = (_Float16)(v.z * dv); o[3] = (_Float16)(v.w * dv);
    ((h4*)xh)[i] = o;
}

// ---------------- aggregation (wave per node, atomic-free, fp16 rows) ----------------

__global__ __launch_bounds__(256) void agg128_kernel(
    const _Float16* __restrict__ xh, const int* __restrict__ offs,
    const int* __restrict__ csr, const float* __restrict__ dinv,
    _Float16* __restrict__ out)
{
    int lane = threadIdx.x & 63;
    int v = blockIdx.x * 4 + (threadIdx.x >> 6);
    const h2* rows = (const h2*)xh;             // 64 h2 per row
    h2 sv = rows[(size_t)v * 64 + lane];
    float ax = (float)sv[0], ay = (float)sv[1];
    int b = offs[v], e = offs[v + 1], j = b;
    for (; j + 8 <= e; j += 8) {
        int s[8];
        #pragma unroll
        for (int q = 0; q < 8; ++q) s[q] = csr[j + q];
        #pragma unroll
        for (int q = 0; q < 8; ++q) {
            h2 t = rows[(size_t)s[q] * 64 + lane];
            ax += (float)t[0]; ay += (float)t[1];
        }
    }
    for (; j < e; ++j) {
        h2 t = rows[(size_t)csr[j] * 64 + lane];
        ax += (float)t[0]; ay += (float)t[1];
    }
    float dv = dinv[v];
    h2 o; o[0] = (_Float16)(ax * dv); o[1] = (_Float16)(ay * dv);
    ((h2*)out)[(size_t)v * 64 + lane] = o;
}

__global__ __launch_bounds__(256) void agg256_kernel(
    const _Float16* __restrict__ hp, const int* __restrict__ offs,
    const int* __restrict__ csr, const float* __restrict__ dinv,
    _Float16* __restrict__ out)
{
    int lane = threadIdx.x & 63;
    int v = blockIdx.x * 4 + (threadIdx.x >> 6);
    const h4* rows = (const h4*)hp;             // 64 h4 per row
    h4 sv = rows[(size_t)v * 64 + lane];
    float a0 = (float)sv[0], a1 = (float)sv[1], a2 = (float)sv[2], a3 = (float)sv[3];
    int b = offs[v], e = offs[v + 1], j = b;
    for (; j + 8 <= e; j += 8) {
        int s[8];
        #pragma unroll
        for (int q = 0; q < 8; ++q) s[q] = csr[j + q];
        #pragma unroll
        for (int q = 0; q < 8; ++q) {
            h4 t = rows[(size_t)s[q] * 64 + lane];
            a0 += (float)t[0]; a1 += (float)t[1]; a2 += (float)t[2]; a3 += (float)t[3];
        }
    }
    for (; j < e; ++j) {
        h4 t = rows[(size_t)csr[j] * 64 + lane];
        a0 += (float)t[0]; a1 += (float)t[1]; a2 += (float)t[2]; a3 += (float)t[3];
    }
    float dv = dinv[v];
    h4 o; o[0] = (_Float16)(a0 * dv); o[1] = (_Float16)(a1 * dv);
    o[2] = (_Float16)(a2 * dv); o[3] = (_Float16)(a3 * dv);
    ((h4*)out)[(size_t)v * 64 + lane] = o;
}

__global__ __launch_bounds__(256) void agg47_lsm_kernel(
    const _Float16* __restrict__ t2, const int* __restrict__ offs,
    const int* __restrict__ csr, const float* __restrict__ dinv,
    const float* __restrict__ bias, float* __restrict__ out)
{
    int lane = threadIdx.x & 63;
    int v = blockIdx.x * 4 + (threadIdx.x >> 6);
    float acc = (float)t2[(size_t)v * COP + lane];     // padded cols read 0
    int b = offs[v], e = offs[v + 1], j = b;
    for (; j + 8 <= e; j += 8) {
        int s[8];
        #pragma unroll
        for (int q = 0; q < 8; ++q) s[q] = csr[j + q];
        #pragma unroll
        for (int q = 0; q < 8; ++q) acc += (float)t2[(size_t)s[q] * COP + lane];
    }
    for (; j < e; ++j) acc += (float)t2[(size_t)csr[j] * COP + lane];
    bool act = lane < CO;
    float val = act ? fmaf(acc, dinv[v], bias[lane]) : -1e30f;
    float m = val;
    #pragma unroll
    for (int o = 32; o > 0; o >>= 1) m = fmaxf(m, __shfl_xor(m, o, 64));
    float ex = act ? expf(val - m) : 0.0f;
    float sum = ex;
    #pragma unroll
    for (int o = 32; o > 0; o >>= 1) sum += __shfl_xor(sum, o, 64);
    if (act) out[(size_t)v * CO + lane] = val - m - logf(sum);
}

// ---------------- MFMA GEMM: C[NN][Ncols] = A[NN][K](fp16) x Wt[Ncols][K](fp16) ----
// 256 threads = 4 waves (2x2). Tile BM=128, BN=64. Wave tile 64x32 = 4x2 frags 16x16.
// mfma_f32_16x16x32_f16: A-frag lane l: row=l&15, k=(l>>4)*8+j; B-frag: col=l&15, same k.
// D: col=l&15, row=(l>>4)*4+reg.

#define LDS_PAD 8

template<int K, bool XFORM, bool EPI_DINV>
__global__ __launch_bounds__(256) void mfma_gemm_kernel(
    const _Float16* __restrict__ A, int lda,
    const _Float16* __restrict__ Wt,
    const float* __restrict__ ss, const float* __restrict__ dinv,
    _Float16* __restrict__ out, int ldo, int ncolsO)
{
    __shared__ __align__(16) _Float16 As[128][32 + LDS_PAD];
    __shared__ __align__(16) _Float16 Bs[64][32 + LDS_PAD];
    __shared__ float SS[2 * K];
    const int row0 = blockIdx.x * 128;
    const int col0 = blockIdx.y * 64;
    const int tid = threadIdx.x;
    if (XFORM) {
        for (int i = tid; i < 2 * K; i += 256) SS[i] = ss[i];
    }
    const int lane = tid & 63;
    const int wv = tid >> 6;
    const int wr = wv >> 1, wc = wv & 1;
    const int fr = lane & 15;
    const int kb = (lane >> 4) * 8;

    f32x4 acc[4][2];
    #pragma unroll
    for (int m = 0; m < 4; ++m)
        #pragma unroll
        for (int n = 0; n < 2; ++n)
            acc[m][n] = (f32x4){0.f, 0.f, 0.f, 0.f};

    if (XFORM) __syncthreads();   // SS visible

    for (int k0 = 0; k0 < K; k0 += 32) {
        // stage A: 128x32 halves, 2 passes of 256 threads x h8
        #pragma unroll
        for (int p = 0; p < 2; ++p) {
            int idx = (p * 256 + tid) * 8;
            int m = idx >> 5, kk = idx & 31;
            int r = row0 + m;
            h8 av = {};
            if (r < NN) av = *(const h8*)&A[(size_t)r * lda + k0 + kk];
            if (XFORM) {
                #pragma unroll
                for (int j = 0; j < 8; ++j) {
                    float a = (float)av[j];
                    a = fmaxf(fmaf(a, SS[k0 + kk + j], SS[K + k0 + kk + j]), 0.0f);
                    av[j] = (_Float16)a;
                }
            }
            *(h8*)&As[m][kk] = av;
        }
        // stage B: 64x32 halves, 1 pass
        {
            int idx = tid * 8;
            int n = idx >> 5, kk = idx & 31;
            h8 bv = *(const h8*)&Wt[(size_t)(col0 + n) * K + k0 + kk];
            *(h8*)&Bs[n][kk] = bv;
        }
        __syncthreads();
        h8 a[4], b[2];
        #pragma unroll
        for (int m = 0; m < 4; ++m)
            a[m] = *(const h8*)&As[wr * 64 + m * 16 + fr][kb];
        #pragma unroll
        for (int n = 0; n < 2; ++n)
            b[n] = *(const h8*)&Bs[wc * 32 + n * 16 + fr][kb];
        #pragma unroll
        for (int m = 0; m < 4; ++m)
            #pragma unroll
            for (int n = 0; n < 2; ++n)
                acc[m][n] = __builtin_amdgcn_mfma_f32_16x16x32_f16(a[m], b[n], acc[m][n], 0, 0, 0);
        __syncthreads();
    }

    const int fq = lane >> 4;
    #pragma unroll
    for (int m = 0; m < 4; ++m) {
        #pragma unroll
        for (int j = 0; j < 4; ++j) {
            int r = row0 + wr * 64 + m * 16 + fq * 4 + j;
            if (r >= NN) continue;
            float dv = EPI_DINV ? dinv[r] : 1.0f;
            #pragma unroll
            for (int n = 0; n < 2; ++n) {
                int c = col0 + wc * 32 + n * 16 + fr;
                if (c < ncolsO) out[(size_t)r * ldo + c] = (_Float16)(acc[m][n][j] * dv);
            }
        }
    }
}

// ---------------- BatchNorm stats (fp16 input, fp32 accumulate) ----------------

__global__ void bn_stats_kernel(const _Float16* __restrict__ h, float* __restrict__ sums) {
    int t = threadIdx.x;
    float s1 = 0.0f, s2 = 0.0f;
    for (int r = blockIdx.x; r < NN; r += gridDim.x) {
        float v = (float)h[(size_t)r * HD + t];
        s1 += v; s2 += v * v;
    }
    atomicAdd(&sums[t], s1);
    atomicAdd(&sums[HD + t], s2);
}

__global__ void bn_finalize_kernel(const float* __restrict__ sums,
                                   const float* __restrict__ g, const float* __restrict__ be,
                                   float* __restrict__ ss) {
    int t = threadIdx.x;
    float mean = sums[t] * (1.0f / NN);
    float var = sums[HD + t] * (1.0f / NN) - mean * mean;
    float sc = g[t] * rsqrtf(var + 1e-5f);
    ss[t] = sc;
    ss[HD + t] = be[t] - mean * sc;
}

// ---------------- launch ----------------

extern "C" void kernel_launch(void* const* d_in, const int* in_sizes, int n_in,
                              void* d_out, int out_size, void* d_ws, size_t ws_size,
                              hipStream_t stream) {
    const float* x   = (const float*)d_in[0];
    const int*   ei  = (const int*)d_in[1];
    const float* W0  = (const float*)d_in[3];
    const float* g0  = (const float*)d_in[5];
    const float* be0 = (const float*)d_in[6];
    const float* W1  = (const float*)d_in[7];
    const float* g1  = (const float*)d_in[9];
    const float* be1 = (const float*)d_in[10];
    const float* W2  = (const float*)d_in[11];
    const float* b2  = (const float*)d_in[12];
    float* out = (float*)d_out;

    const int* src = ei;            // edge_index[0]
    const int* dst = ei + NE;       // edge_index[1]

    // workspace layout
    const size_t S = 51200000;                        // 100000*256*2 bytes
    char* ws = (char*)d_ws;
    _Float16* S1   = (_Float16*)ws;                   // t1 / t2 slot
    _Float16* xh   = S1;                              // [NN][128] fp16
    _Float16* a0   = S1 + 12800000;                   // [NN][128] fp16
    _Float16* S2   = (_Float16*)(ws + S);             // h0 / h1 slot
    int*   csr  = (int*)  (ws + 2 * S);               // 12.8MB
    int*   offs = (int*)  (ws + 2 * S + 12800000);
    int*   cnt  = (int*)  (ws + 2 * S + 13200064);
    int*   cur  = (int*)  (ws + 2 * S + 13600064);
    float* dinv = (float*)(ws + 2 * S + 14000064);
    float* bns  = (float*)(ws + 2 * S + 14400064);
    float* ssb  = (float*)(ws + 2 * S + 14402112);
    int*   bsum = (int*)  (ws + 2 * S + 14404160);    // 512+1 ints
    _Float16* wt0 = (_Float16*)(ws + 2 * S + 14406272);   // [256][128]
    _Float16* wt1 = (_Float16*)(ws + 2 * S + 14471872);   // [256][256]
    _Float16* wt2 = (_Float16*)(ws + 2 * S + 14602944);   // [64][256]

    const int NB = (NN + 255) / 256;   // 391
    const int EB = (NE + 255) / 256;   // 12500

    // CSR build
    hipMemsetAsync(cnt, 0, NN * sizeof(int), stream);
    count_deg_kernel<<<EB, 256, 0, stream>>>(dst, cnt);
    dinv_kernel<<<NB, 256, 0, stream>>>(cnt, dinv);
    scan1_kernel<<<NB, 256, 0, stream>>>(cnt, offs, bsum);
    scan2_kernel<<<1, 512, 0, stream>>>(bsum, NB);
    scan3_kernel<<<NB, 256, 0, stream>>>(offs, bsum, NB);
    hipMemcpyAsync(cur, offs, NN * sizeof(int), hipMemcpyDeviceToDevice, stream);
    fill_csr_kernel<<<EB, 256, 0, stream>>>(src, dst, cur, csr);

    // weights -> fp16 transposed
    wtrans_kernel<FIN><<<(256 * FIN + 255) / 256, 256, 0, stream>>>(W0, wt0, HD, HD);
    wtrans_kernel<HD><<<(256 * HD + 255) / 256, 256, 0, stream>>>(W1, wt1, HD, HD);
    wtrans_kernel<HD><<<(COP * HD + 255) / 256, 256, 0, stream>>>(W2, wt2, CO, COP);

    const int MB = (NN + 127) / 128;   // 782

    // Layer 0 (reassociated): a0 = D^-1/2 (A+I) D^-1/2 x; h0 = a0 @ W0
    conv_x_kernel<<<(NN * FIN / 4 + 255) / 256, 256, 0, stream>>>(x, dinv, xh);
    agg128_kernel<<<NN / 4, 256, 0, stream>>>(xh, offs, csr, dinv, a0);
    mfma_gemm_kernel<FIN, false, false><<<dim3(MB, 4), 256, 0, stream>>>(
        a0, FIN, wt0, nullptr, dinv, S2, HD, HD);               // h0 -> S2

    hipMemsetAsync(bns, 0, 2 * HD * sizeof(float), stream);
    bn_stats_kernel<<<1024, 256, 0, stream>>>(S2, bns);
    bn_finalize_kernel<<<1, HD, 0, stream>>>(bns, g0, be0, ssb);

    // Layer 1: t1 = dinv * (relu(bn(h0)) @ W1); h1 = dinv*(A+I)t1
    mfma_gemm_kernel<HD, true, true><<<dim3(MB, 4), 256, 0, stream>>>(
        S2, HD, wt1, ssb, dinv, S1, HD, HD);                    // t1 -> S1
    agg256_kernel<<<NN / 4, 256, 0, stream>>>(S1, offs, csr, dinv, S2);  // h1 -> S2

    hipMemsetAsync(bns, 0, 2 * HD * sizeof(float), stream);
    bn_stats_kernel<<<1024, 256, 0, stream>>>(S2, bns);
    bn_finalize_kernel<<<1, HD, 0, stream>>>(bns, g1, be1, ssb);

    // Layer 2: t2 = dinv * (relu(bn(h1)) @ W2), rows padded to 64; agg + log_softmax
    mfma_gemm_kernel<HD, true, true><<<dim3(MB, 1), 256, 0, stream>>>(
        S2, HD, wt2, ssb, dinv, S1, COP, COP);                  // t2 -> S1
    agg47_lsm_kernel<<<NN / 4, 256, 0, stream>>>(S1, offs, csr, dinv, b2, out);
}

// Round 4
// 1066.936 us; speedup vs baseline: 2.1147x; 1.0118x over previous
//
#include <hip/hip_runtime.h>
#include <math.h>

#define NN 100000
#define NE 3200000
#define FIN 128
#define HD 256
#define CO 47
#define COP 64   // padded row for layer-2 gather (one 128B line)

typedef _Float16 h2 __attribute__((ext_vector_type(2)));
typedef _Float16 h4 __attribute__((ext_vector_type(4)));
typedef _Float16 h8 __attribute__((ext_vector_type(8)));
typedef float f32x4 __attribute__((ext_vector_type(4)));

// ---------------- CSR build (8-way replicated counters: blockIdx&7 ~ XCD) ----------

__global__ void count8_kernel(const int* __restrict__ dst, int* __restrict__ cnt8) {
    int e = blockIdx.x * 256 + threadIdx.x;
    if (e < NE) atomicAdd(&cnt8[(blockIdx.x & 7) * NN + dst[e]], 1);
}

__global__ void degsum_kernel(const int* __restrict__ cnt8, int* __restrict__ cnt,
                              float* __restrict__ dinv) {
    int i = blockIdx.x * 256 + threadIdx.x;
    if (i >= NN) return;
    int s = 0;
    #pragma unroll
    for (int x = 0; x < 8; ++x) s += cnt8[x * NN + i];
    cnt[i] = s;
    dinv[i] = rsqrtf((float)s + 1.0f);   // +1 self loop
}

// hierarchical exclusive scan: cnt[NN] -> offs[NN+1]
__global__ void scan1_kernel(const int* __restrict__ cnt, int* __restrict__ offs,
                             int* __restrict__ bsum) {
    __shared__ int tmp[256];
    int t = threadIdx.x;
    int i = blockIdx.x * 256 + t;
    int v = (i < NN) ? cnt[i] : 0;
    tmp[t] = v;
    __syncthreads();
    #pragma unroll
    for (int off = 1; off < 256; off <<= 1) {
        int u = (t >= off) ? tmp[t - off] : 0;
        __syncthreads();
        tmp[t] += u;
        __syncthreads();
    }
    if (i < NN) offs[i] = tmp[t] - v;          // exclusive within block
    if (t == 255) bsum[blockIdx.x] = tmp[255];
}

__global__ void scan2_kernel(int* __restrict__ bsum, int nb) {
    __shared__ int tmp[512];
    int t = threadIdx.x;
    int v = (t < nb) ? bsum[t] : 0;
    tmp[t] = v;
    __syncthreads();
    #pragma unroll
    for (int off = 1; off < 512; off <<= 1) {
        int u = (t >= off) ? tmp[t - off] : 0;
        __syncthreads();
        tmp[t] += u;
        __syncthreads();
    }
    if (t < nb) bsum[t] = tmp[t] - v;          // exclusive
    if (t == nb - 1) bsum[nb] = tmp[t];        // total
}

__global__ void scan3_kernel(int* __restrict__ offs, const int* __restrict__ bsum, int nb) {
    int i = blockIdx.x * 256 + threadIdx.x;
    if (i < NN) offs[i] += bsum[i >> 8];
    if (i == 0) offs[NN] = bsum[nb];
}

// cnt8 -> absolute start slots per (replica, node)
__global__ void mkstart_kernel(int* __restrict__ cnt8, const int* __restrict__ offs) {
    int i = blockIdx.x * 256 + threadIdx.x;
    if (i >= NN) return;
    int base = offs[i];
    #pragma unroll
    for (int x = 0; x < 8; ++x) {
        int t = cnt8[x * NN + i];
        cnt8[x * NN + i] = base;
        base += t;
    }
}

__global__ void fill_csr_kernel(const int* __restrict__ src, const int* __restrict__ dst,
                                int* __restrict__ start8, int* __restrict__ csr) {
    int e = blockIdx.x * 256 + threadIdx.x;
    if (e >= NE) return;
    int p = atomicAdd(&start8[(blockIdx.x & 7) * NN + dst[e]], 1);
    csr[p] = src[e];
}

// ---------------- weight convert: Wt[n][k] = (fp16) W[k][n], rows >= N zeroed ----

template<int K>
__global__ void wtrans_kernel(const float* __restrict__ W, _Float16* __restrict__ Wt,
                              int N, int NP) {
    int i = blockIdx.x * 256 + threadIdx.x;
    if (i >= NP * K) return;
    int n = i / K, k = i % K;
    float v = (n < N) ? W[(size_t)k * N + n] : 0.0f;
    Wt[i] = (_Float16)v;
}

// ---------------- x -> fp16, pre-scaled by dinv ----------------

__global__ void conv_x_kernel(const float* __restrict__ x, const float* __restrict__ dinv,
                              _Float16* __restrict__ xh) {
    int i = blockIdx.x * 256 + threadIdx.x;     // over NN*FIN/4 float4s
    if (i >= NN * FIN / 4) return;
    int r = i >> 5;                             // /(FIN/4)
    float4 v = ((const float4*)x)[i];
    float dv = dinv[r];
    h4 o; o[0] = (_Float16)(v.x * dv); o[1] = (_Float16)(v.y * dv);
    o[2] = (_Float16)(v.z * dv); o[3] = (_Float16)(v.w * dv);
    ((h4*)xh)[i] = o;
}

// ---------------- aggregation (wave per node, atomic-free, fp16 rows) ----------------

__global__ __launch_bounds__(256) void agg128_kernel(
    const _Float16* __restrict__ xh, const int* __restrict__ offs,
    const int* __restrict__ csr, const float* __restrict__ dinv,
    _Float16* __restrict__ out)
{
    int lane = threadIdx.x & 63;
    int v = blockIdx.x * 4 + (threadIdx.x >> 6);
    const h2* rows = (const h2*)xh;             // 64 h2 per row
    h2 sv = rows[(size_t)v * 64 + lane];
    float ax = (float)sv[0], ay = (float)sv[1];
    int b = offs[v], e = offs[v + 1], j = b;
    for (; j + 8 <= e; j += 8) {
        int s[8];
        #pragma unroll
        for (int q = 0; q < 8; ++q) s[q] = csr[j + q];
        #pragma unroll
        for (int q = 0; q < 8; ++q) {
            h2 t = rows[(size_t)s[q] * 64 + lane];
            ax += (float)t[0]; ay += (float)t[1];
        }
    }
    for (; j < e; ++j) {
        h2 t = rows[(size_t)csr[j] * 64 + lane];
        ax += (float)t[0]; ay += (float)t[1];
    }
    float dv = dinv[v];
    h2 o; o[0] = (_Float16)(ax * dv); o[1] = (_Float16)(ay * dv);
    ((h2*)out)[(size_t)v * 64 + lane] = o;
}

__global__ __launch_bounds__(256) void agg256_kernel(
    const _Float16* __restrict__ hp, const int* __restrict__ offs,
    const int* __restrict__ csr, const float* __restrict__ dinv,
    _Float16* __restrict__ out)
{
    int lane = threadIdx.x & 63;
    int v = blockIdx.x * 4 + (threadIdx.x >> 6);
    const h4* rows = (const h4*)hp;             // 64 h4 per row
    h4 sv = rows[(size_t)v * 64 + lane];
    float a0 = (float)sv[0], a1 = (float)sv[1], a2 = (float)sv[2], a3 = (float)sv[3];
    int b = offs[v], e = offs[v + 1], j = b;
    for (; j + 8 <= e; j += 8) {
        int s[8];
        #pragma unroll
        for (int q = 0; q < 8; ++q) s[q] = csr[j + q];
        #pragma unroll
        for (int q = 0; q < 8; ++q) {
            h4 t = rows[(size_t)s[q] * 64 + lane];
            a0 += (float)t[0]; a1 += (float)t[1]; a2 += (float)t[2]; a3 += (float)t[3];
        }
    }
    for (; j < e; ++j) {
        h4 t = rows[(size_t)csr[j] * 64 + lane];
        a0 += (float)t[0]; a1 += (float)t[1]; a2 += (float)t[2]; a3 += (float)t[3];
    }
    float dv = dinv[v];
    h4 o; o[0] = (_Float16)(a0 * dv); o[1] = (_Float16)(a1 * dv);
    o[2] = (_Float16)(a2 * dv); o[3] = (_Float16)(a3 * dv);
    ((h4*)out)[(size_t)v * 64 + lane] = o;
}

__global__ __launch_bounds__(256) void agg47_lsm_kernel(
    const _Float16* __restrict__ t2, const int* __restrict__ offs,
    const int* __restrict__ csr, const float* __restrict__ dinv,
    const float* __restrict__ bias, float* __restrict__ out)
{
    int lane = threadIdx.x & 63;
    int v = blockIdx.x * 4 + (threadIdx.x >> 6);
    float acc = (float)t2[(size_t)v * COP + lane];     // padded cols read 0
    int b = offs[v], e = offs[v + 1], j = b;
    for (; j + 8 <= e; j += 8) {
        int s[8];
        #pragma unroll
        for (int q = 0; q < 8; ++q) s[q] = csr[j + q];
        #pragma unroll
        for (int q = 0; q < 8; ++q) acc += (float)t2[(size_t)s[q] * COP + lane];
    }
    for (; j < e; ++j) acc += (float)t2[(size_t)csr[j] * COP + lane];
    bool act = lane < CO;
    float val = act ? fmaf(acc, dinv[v], bias[lane]) : -1e30f;
    float m = val;
    #pragma unroll
    for (int o = 32; o > 0; o >>= 1) m = fmaxf(m, __shfl_xor(m, o, 64));
    float ex = act ? expf(val - m) : 0.0f;
    float sum = ex;
    #pragma unroll
    for (int o = 32; o > 0; o >>= 1) sum += __shfl_xor(sum, o, 64);
    if (act) out[(size_t)v * CO + lane] = val - m - logf(sum);
}

// ---------------- MFMA GEMM: C[NN][Ncols] = A[NN][K](fp16) x Wt[Ncols][K](fp16) ----

#define LDS_PAD 8

template<int K, bool XFORM, bool EPI_DINV>
__global__ __launch_bounds__(256) void mfma_gemm_kernel(
    const _Float16* __restrict__ A, int lda,
    const _Float16* __restrict__ Wt,
    const float* __restrict__ ss, const float* __restrict__ dinv,
    _Float16* __restrict__ out, int ldo, int ncolsO)
{
    __shared__ __align__(16) _Float16 As[128][32 + LDS_PAD];
    __shared__ __align__(16) _Float16 Bs[64][32 + LDS_PAD];
    __shared__ float SS[2 * K];
    const int row0 = blockIdx.x * 128;
    const int col0 = blockIdx.y * 64;
    const int tid = threadIdx.x;
    if (XFORM) {
        for (int i = tid; i < 2 * K; i += 256) SS[i] = ss[i];
    }
    const int lane = tid & 63;
    const int wv = tid >> 6;
    const int wr = wv >> 1, wc = wv & 1;
    const int fr = lane & 15;
    const int kb = (lane >> 4) * 8;

    f32x4 acc[4][2];
    #pragma unroll
    for (int m = 0; m < 4; ++m)
        #pragma unroll
        for (int n = 0; n < 2; ++n)
            acc[m][n] = (f32x4){0.f, 0.f, 0.f, 0.f};

    if (XFORM) __syncthreads();   // SS visible

    for (int k0 = 0; k0 < K; k0 += 32) {
        #pragma unroll
        for (int p = 0; p < 2; ++p) {
            int idx = (p * 256 + tid) * 8;
            int m = idx >> 5, kk = idx & 31;
            int r = row0 + m;
            h8 av = {};
            if (r < NN) av = *(const h8*)&A[(size_t)r * lda + k0 + kk];
            if (XFORM) {
                #pragma unroll
                for (int j = 0; j < 8; ++j) {
                    float a = (float)av[j];
                    a = fmaxf(fmaf(a, SS[k0 + kk + j], SS[K + k0 + kk + j]), 0.0f);
                    av[j] = (_Float16)a;
                }
            }
            *(h8*)&As[m][kk] = av;
        }
        {
            int idx = tid * 8;
            int n = idx >> 5, kk = idx & 31;
            h8 bv = *(const h8*)&Wt[(size_t)(col0 + n) * K + k0 + kk];
            *(h8*)&Bs[n][kk] = bv;
        }
        __syncthreads();
        h8 a[4], b[2];
        #pragma unroll
        for (int m = 0; m < 4; ++m)
            a[m] = *(const h8*)&As[wr * 64 + m * 16 + fr][kb];
        #pragma unroll
        for (int n = 0; n < 2; ++n)
            b[n] = *(const h8*)&Bs[wc * 32 + n * 16 + fr][kb];
        #pragma unroll
        for (int m = 0; m < 4; ++m)
            #pragma unroll
            for (int n = 0; n < 2; ++n)
                acc[m][n] = __builtin_amdgcn_mfma_f32_16x16x32_f16(a[m], b[n], acc[m][n], 0, 0, 0);
        __syncthreads();
    }

    const int fq = lane >> 4;
    #pragma unroll
    for (int m = 0; m < 4; ++m) {
        #pragma unroll
        for (int j = 0; j < 4; ++j) {
            int r = row0 + wr * 64 + m * 16 + fq * 4 + j;
            if (r >= NN) continue;
            float dv = EPI_DINV ? dinv[r] : 1.0f;
            #pragma unroll
            for (int n = 0; n < 2; ++n) {
                int c = col0 + wc * 32 + n * 16 + fr;
                if (c < ncolsO) out[(size_t)r * ldo + c] = (_Float16)(acc[m][n][j] * dv);
            }
        }
    }
}

// ---------------- BatchNorm stats (fp16 input, fp32 accumulate) ----------------

__global__ void bn_stats_kernel(const _Float16* __restrict__ h, float* __restrict__ sums) {
    int t = threadIdx.x;
    float s1 = 0.0f, s2 = 0.0f;
    for (int r = blockIdx.x; r < NN; r += gridDim.x) {
        float v = (float)h[(size_t)r * HD + t];
        s1 += v; s2 += v * v;
    }
    atomicAdd(&sums[t], s1);
    atomicAdd(&sums[HD + t], s2);
}

__global__ void bn_finalize_kernel(const float* __restrict__ sums,
                                   const float* __restrict__ g, const float* __restrict__ be,
                                   float* __restrict__ ss) {
    int t = threadIdx.x;
    float mean = sums[t] * (1.0f / NN);
    float var = sums[HD + t] * (1.0f / NN) - mean * mean;
    float sc = g[t] * rsqrtf(var + 1e-5f);
    ss[t] = sc;
    ss[HD + t] = be[t] - mean * sc;
}

// ---------------- launch ----------------

extern "C" void kernel_launch(void* const* d_in, const int* in_sizes, int n_in,
                              void* d_out, int out_size, void* d_ws, size_t ws_size,
                              hipStream_t stream) {
    const float* x   = (const float*)d_in[0];
    const int*   ei  = (const int*)d_in[1];
    const float* W0  = (const float*)d_in[3];
    const float* g0  = (const float*)d_in[5];
    const float* be0 = (const float*)d_in[6];
    const float* W1  = (const float*)d_in[7];
    const float* g1  = (const float*)d_in[9];
    const float* be1 = (const float*)d_in[10];
    const float* W2  = (const float*)d_in[11];
    const float* b2  = (const float*)d_in[12];
    float* out = (float*)d_out;

    const int* src = ei;            // edge_index[0]
    const int* dst = ei + NE;       // edge_index[1]

    // workspace layout
    const size_t S = 51200000;                        // 100000*256*2 bytes
    char* ws = (char*)d_ws;
    _Float16* S1   = (_Float16*)ws;                   // t1 / t2 slot
    _Float16* xh   = S1;                              // [NN][128] fp16
    _Float16* a0   = S1 + 12800000;                   // [NN][128] fp16
    _Float16* S2   = (_Float16*)(ws + S);             // h0 / h1 slot
    int*   csr  = (int*)  (ws + 2 * S);               // 12.8MB
    int*   offs = (int*)  (ws + 2 * S + 12800000);
    int*   cnt  = (int*)  (ws + 2 * S + 13200064);
    float* dinv = (float*)(ws + 2 * S + 13600064);
    float* bns  = (float*)(ws + 2 * S + 14000064);
    float* ssb  = (float*)(ws + 2 * S + 14002112);
    int*   bsum = (int*)  (ws + 2 * S + 14004160);    // 512+1 ints
    _Float16* wt0 = (_Float16*)(ws + 2 * S + 14006272);   // [256][128]
    _Float16* wt1 = (_Float16*)(ws + 2 * S + 14071872);   // [256][256]
    _Float16* wt2 = (_Float16*)(ws + 2 * S + 14202944);   // [64][256]
    int*   cnt8 = (int*)  (ws + 2 * S + 14235712);    // 8*NN ints = 3.2MB

    const int NB = (NN + 255) / 256;   // 391
    const int EB = (NE + 255) / 256;   // 12500

    // CSR build: replicated counters (replica = blockIdx&7 ~ XCD)
    hipMemsetAsync(cnt8, 0, 8 * NN * sizeof(int), stream);
    count8_kernel<<<EB, 256, 0, stream>>>(dst, cnt8);
    degsum_kernel<<<NB, 256, 0, stream>>>(cnt8, cnt, dinv);
    scan1_kernel<<<NB, 256, 0, stream>>>(cnt, offs, bsum);
    scan2_kernel<<<1, 512, 0, stream>>>(bsum, NB);
    scan3_kernel<<<NB, 256, 0, stream>>>(offs, bsum, NB);
    mkstart_kernel<<<NB, 256, 0, stream>>>(cnt8, offs);
    fill_csr_kernel<<<EB, 256, 0, stream>>>(src, dst, cnt8, csr);

    // weights -> fp16 transposed
    wtrans_kernel<FIN><<<(256 * FIN + 255) / 256, 256, 0, stream>>>(W0, wt0, HD, HD);
    wtrans_kernel<HD><<<(256 * HD + 255) / 256, 256, 0, stream>>>(W1, wt1, HD, HD);
    wtrans_kernel<HD><<<(COP * HD + 255) / 256, 256, 0, stream>>>(W2, wt2, CO, COP);

    const int MB = (NN + 127) / 128;   // 782

    // Layer 0 (reassociated): a0 = D^-1/2 (A+I) D^-1/2 x; h0 = a0 @ W0
    conv_x_kernel<<<(NN * FIN / 4 + 255) / 256, 256, 0, stream>>>(x, dinv, xh);
    agg128_kernel<<<NN / 4, 256, 0, stream>>>(xh, offs, csr, dinv, a0);
    mfma_gemm_kernel<FIN, false, false><<<dim3(MB, 4), 256, 0, stream>>>(
        a0, FIN, wt0, nullptr, dinv, S2, HD, HD);               // h0 -> S2

    hipMemsetAsync(bns, 0, 2 * HD * sizeof(float), stream);
    bn_stats_kernel<<<1024, 256, 0, stream>>>(S2, bns);
    bn_finalize_kernel<<<1, HD, 0, stream>>>(bns, g0, be0, ssb);

    // Layer 1: t1 = dinv * (relu(bn(h0)) @ W1); h1 = dinv*(A+I)t1
    mfma_gemm_kernel<HD, true, true><<<dim3(MB, 4), 256, 0, stream>>>(
        S2, HD, wt1, ssb, dinv, S1, HD, HD);                    // t1 -> S1
    agg256_kernel<<<NN / 4, 256, 0, stream>>>(S1, offs, csr, dinv, S2);  // h1 -> S2

    hipMemsetAsync(bns, 0, 2 * HD * sizeof(float), stream);
    bn_stats_kernel<<<1024, 256, 0, stream>>>(S2, bns);
    bn_finalize_kernel<<<1, HD, 0, stream>>>(bns, g1, be1, ssb);

    // Layer 2: t2 = dinv * (relu(bn(h1)) @ W2), rows padded to 64; agg + log_softmax
    mfma_gemm_kernel<HD, true, true><<<dim3(MB, 1), 256, 0, stream>>>(
        S2, HD, wt2, ssb, dinv, S1, COP, COP);                  // t2 -> S1
    agg47_lsm_kernel<<<NN / 4, 256, 0, stream>>>(S1, offs, csr, dinv, b2, out);
}

// Round 5
// 744.327 us; speedup vs baseline: 3.0312x; 1.4334x over previous
//
#include <hip/hip_runtime.h>
#include <math.h>

#define NN 100000
#define NE 3200000
#define FIN 128
#define HD 256
#define CO 47
#define COP 64     // padded row for layer-2 gather (one 128B line)
#define NBKT 196   // buckets of 512 nodes: dst>>9
#define G 1024     // partition blocks
#define CHUNK 3125 // NE / G exactly

typedef _Float16 h2 __attribute__((ext_vector_type(2)));
typedef _Float16 h4 __attribute__((ext_vector_type(4)));
typedef _Float16 h8 __attribute__((ext_vector_type(8)));
typedef float f32x4 __attribute__((ext_vector_type(4)));

// ---------------- CSR build via bucketed counting sort ----------------

__global__ __launch_bounds__(256) void hist_kernel(const int* __restrict__ dst,
                                                   int* __restrict__ hist) {
    __shared__ int h[NBKT];
    int tid = threadIdx.x;
    for (int i = tid; i < NBKT; i += 256) h[i] = 0;
    __syncthreads();
    int base = blockIdx.x * CHUNK;
    for (int i = tid; i < CHUNK; i += 256)
        atomicAdd(&h[dst[base + i] >> 9], 1);
    __syncthreads();
    for (int i = tid; i < NBKT; i += 256) hist[i * G + blockIdx.x] = h[i];
}

// generic hierarchical exclusive scan over n elements (n multiple coverage by 256-blocks)
__global__ void scan1_kernel(const int* __restrict__ in, int* __restrict__ out,
                             int* __restrict__ bsum, int n) {
    __shared__ int tmp[256];
    int t = threadIdx.x;
    int i = blockIdx.x * 256 + t;
    int v = (i < n) ? in[i] : 0;
    tmp[t] = v;
    __syncthreads();
    #pragma unroll
    for (int off = 1; off < 256; off <<= 1) {
        int u = (t >= off) ? tmp[t - off] : 0;
        __syncthreads();
        tmp[t] += u;
        __syncthreads();
    }
    if (i < n) out[i] = tmp[t] - v;            // exclusive within block
    if (t == 255) bsum[blockIdx.x] = tmp[255];
}

__global__ void scan2_kernel(int* __restrict__ bsum, int nb) {
    __shared__ int tmp[1024];
    int t = threadIdx.x;
    int v = (t < nb) ? bsum[t] : 0;
    tmp[t] = v;
    __syncthreads();
    #pragma unroll
    for (int off = 1; off < 1024; off <<= 1) {
        int u = (t >= off) ? tmp[t - off] : 0;
        __syncthreads();
        tmp[t] += u;
        __syncthreads();
    }
    if (t < nb) bsum[t] = tmp[t] - v;          // exclusive
    if (t == nb - 1) bsum[nb] = tmp[t];        // total
}

__global__ void scan3_kernel(int* __restrict__ out, const int* __restrict__ bsum,
                             int nb, int n) {
    int i = blockIdx.x * 256 + threadIdx.x;
    if (i < n) out[i] += bsum[i >> 8];
    if (i == 0) out[n] = bsum[nb];             // total sentinel
}

__global__ __launch_bounds__(256) void scatter_kernel(const int* __restrict__ src,
                                                      const int* __restrict__ dst,
                                                      const int* __restrict__ hscan,
                                                      int* __restrict__ epk) {
    __shared__ int cur[NBKT];
    int tid = threadIdx.x;
    for (int i = tid; i < NBKT; i += 256) cur[i] = hscan[i * G + blockIdx.x];
    __syncthreads();
    int base = blockIdx.x * CHUNK;
    for (int i = tid; i < CHUNK; i += 256) {
        int e = base + i;
        int d = dst[e];
        int slot = atomicAdd(&cur[d >> 9], 1);
        epk[slot] = ((d & 511) << 17) | src[e];
    }
}

// one block per bucket: degrees, local scan -> offs/dinv, coalesced-region csr fill
__global__ __launch_bounds__(256) void bucket_fill_kernel(
    const int* __restrict__ hscan, const int* __restrict__ epk,
    int* __restrict__ csr, int* __restrict__ offs, float* __restrict__ dinv)
{
    __shared__ int deg[512], cur[512], a0[512], a1[512];
    int tid = threadIdx.x, b = blockIdx.x;
    int ebeg = hscan[b * G], eend = hscan[(b + 1) * G];
    deg[tid] = 0; deg[tid + 256] = 0;
    __syncthreads();
    for (int e = ebeg + tid; e < eend; e += 256)
        atomicAdd(&deg[((unsigned)epk[e]) >> 17], 1);
    __syncthreads();
    a0[tid] = deg[tid]; a0[tid + 256] = deg[tid + 256];
    __syncthreads();
    int* pin = a0; int* pout = a1;
    for (int off = 1; off < 512; off <<= 1) {
        #pragma unroll
        for (int q = 0; q < 2; ++q) {
            int p = tid + q * 256;
            pout[p] = pin[p] + ((p >= off) ? pin[p - off] : 0);
        }
        __syncthreads();
        int* t = pin; pin = pout; pout = t;
    }
    // pin = inclusive scan
    #pragma unroll
    for (int q = 0; q < 2; ++q) {
        int i = tid + q * 256;
        int excl = pin[i] - deg[i];
        cur[i] = excl;
        int node = b * 512 + i;
        if (node < NN) {
            offs[node] = ebeg + excl;
            dinv[node] = rsqrtf((float)deg[i] + 1.0f);
        }
    }
    if (b == 0 && tid == 0) offs[NN] = NE;
    __syncthreads();
    for (int e = ebeg + tid; e < eend; e += 256) {
        int pk = epk[e];
        int p = atomicAdd(&cur[((unsigned)pk) >> 17], 1);
        csr[ebeg + p] = pk & 0x1FFFF;
    }
}

// ---------------- weight convert: Wt[n][k] = (fp16) W[k][n], rows >= N zeroed ----

template<int K>
__global__ void wtrans_kernel(const float* __restrict__ W, _Float16* __restrict__ Wt,
                              int N, int NP) {
    int i = blockIdx.x * 256 + threadIdx.x;
    if (i >= NP * K) return;
    int n = i / K, k = i % K;
    float v = (n < N) ? W[(size_t)k * N + n] : 0.0f;
    Wt[i] = (_Float16)v;
}

// ---------------- x -> fp16, pre-scaled by dinv ----------------

__global__ void conv_x_kernel(const float* __restrict__ x, const float* __restrict__ dinv,
                              _Float16* __restrict__ xh) {
    int i = blockIdx.x * 256 + threadIdx.x;     // over NN*FIN/4 float4s
    if (i >= NN * FIN / 4) return;
    int r = i >> 5;                             // /(FIN/4)
    float4 v = ((const float4*)x)[i];
    float dv = dinv[r];
    h4 o; o[0] = (_Float16)(v.x * dv); o[1] = (_Float16)(v.y * dv);
    o[2] = (_Float16)(v.z * dv); o[3] = (_Float16)(v.w * dv);
    ((h4*)xh)[i] = o;
}

// ---------------- aggregation (wave per node, atomic-free, fp16 rows) ----------------

__global__ __launch_bounds__(256) void agg128_kernel(
    const _Float16* __restrict__ xh, const int* __restrict__ offs,
    const int* __restrict__ csr, const float* __restrict__ dinv,
    _Float16* __restrict__ out)
{
    int lane = threadIdx.x & 63;
    int v = blockIdx.x * 4 + (threadIdx.x >> 6);
    const h2* rows = (const h2*)xh;             // 64 h2 per row
    h2 sv = rows[(size_t)v * 64 + lane];
    float ax = (float)sv[0], ay = (float)sv[1];
    int b = offs[v], e = offs[v + 1], j = b;
    for (; j + 8 <= e; j += 8) {
        int s[8];
        #pragma unroll
        for (int q = 0; q < 8; ++q) s[q] = csr[j + q];
        #pragma unroll
        for (int q = 0; q < 8; ++q) {
            h2 t = rows[(size_t)s[q] * 64 + lane];
            ax += (float)t[0]; ay += (float)t[1];
        }
    }
    for (; j < e; ++j) {
        h2 t = rows[(size_t)csr[j] * 64 + lane];
        ax += (float)t[0]; ay += (float)t[1];
    }
    float dv = dinv[v];
    h2 o; o[0] = (_Float16)(ax * dv); o[1] = (_Float16)(ay * dv);
    ((h2*)out)[(size_t)v * 64 + lane] = o;
}

__global__ __launch_bounds__(256) void agg256_kernel(
    const _Float16* __restrict__ hp, const int* __restrict__ offs,
    const int* __restrict__ csr, const float* __restrict__ dinv,
    _Float16* __restrict__ out)
{
    int lane = threadIdx.x & 63;
    int v = blockIdx.x * 4 + (threadIdx.x >> 6);
    const h4* rows = (const h4*)hp;             // 64 h4 per row
    h4 sv = rows[(size_t)v * 64 + lane];
    float a0 = (float)sv[0], a1 = (float)sv[1], a2 = (float)sv[2], a3 = (float)sv[3];
    int b = offs[v], e = offs[v + 1], j = b;
    for (; j + 8 <= e; j += 8) {
        int s[8];
        #pragma unroll
        for (int q = 0; q < 8; ++q) s[q] = csr[j + q];
        #pragma unroll
        for (int q = 0; q < 8; ++q) {
            h4 t = rows[(size_t)s[q] * 64 + lane];
            a0 += (float)t[0]; a1 += (float)t[1]; a2 += (float)t[2]; a3 += (float)t[3];
        }
    }
    for (; j < e; ++j) {
        h4 t = rows[(size_t)csr[j] * 64 + lane];
        a0 += (float)t[0]; a1 += (float)t[1]; a2 += (float)t[2]; a3 += (float)t[3];
    }
    float dv = dinv[v];
    h4 o; o[0] = (_Float16)(a0 * dv); o[1] = (_Float16)(a1 * dv);
    o[2] = (_Float16)(a2 * dv); o[3] = (_Float16)(a3 * dv);
    ((h4*)out)[(size_t)v * 64 + lane] = o;
}

__global__ __launch_bounds__(256) void agg47_lsm_kernel(
    const _Float16* __restrict__ t2, const int* __restrict__ offs,
    const int* __restrict__ csr, const float* __restrict__ dinv,
    const float* __restrict__ bias, float* __restrict__ out)
{
    int lane = threadIdx.x & 63;
    int v = blockIdx.x * 4 + (threadIdx.x >> 6);
    float acc = (float)t2[(size_t)v * COP + lane];     // padded cols read 0
    int b = offs[v], e = offs[v + 1], j = b;
    for (; j + 8 <= e; j += 8) {
        int s[8];
        #pragma unroll
        for (int q = 0; q < 8; ++q) s[q] = csr[j + q];
        #pragma unroll
        for (int q = 0; q < 8; ++q) acc += (float)t2[(size_t)s[q] * COP + lane];
    }
    for (; j < e; ++j) acc += (float)t2[(size_t)csr[j] * COP + lane];
    bool act = lane < CO;
    float val = act ? fmaf(acc, dinv[v], bias[lane]) : -1e30f;
    float m = val;
    #pragma unroll
    for (int o = 32; o > 0; o >>= 1) m = fmaxf(m, __shfl_xor(m, o, 64));
    float ex = act ? expf(val - m) : 0.0f;
    float sum = ex;
    #pragma unroll
    for (int o = 32; o > 0; o >>= 1) sum += __shfl_xor(sum, o, 64);
    if (act) out[(size_t)v * CO + lane] = val - m - logf(sum);
}

// ---------------- MFMA GEMM: C[NN][Ncols] = A[NN][K](fp16) x Wt[Ncols][K](fp16) ----

#define LDS_PAD 8

template<int K, bool XFORM, bool EPI_DINV>
__global__ __launch_bounds__(256) void mfma_gemm_kernel(
    const _Float16* __restrict__ A, int lda,
    const _Float16* __restrict__ Wt,
    const float* __restrict__ ss, const float* __restrict__ dinv,
    _Float16* __restrict__ out, int ldo, int ncolsO)
{
    __shared__ __align__(16) _Float16 As[128][32 + LDS_PAD];
    __shared__ __align__(16) _Float16 Bs[64][32 + LDS_PAD];
    __shared__ float SS[2 * K];
    const int row0 = blockIdx.x * 128;
    const int col0 = blockIdx.y * 64;
    const int tid = threadIdx.x;
    if (XFORM) {
        for (int i = tid; i < 2 * K; i += 256) SS[i] = ss[i];
    }
    const int lane = tid & 63;
    const int wv = tid >> 6;
    const int wr = wv >> 1, wc = wv & 1;
    const int fr = lane & 15;
    const int kb = (lane >> 4) * 8;

    f32x4 acc[4][2];
    #pragma unroll
    for (int m = 0; m < 4; ++m)
        #pragma unroll
        for (int n = 0; n < 2; ++n)
            acc[m][n] = (f32x4){0.f, 0.f, 0.f, 0.f};

    if (XFORM) __syncthreads();   // SS visible

    for (int k0 = 0; k0 < K; k0 += 32) {
        #pragma unroll
        for (int p = 0; p < 2; ++p) {
            int idx = (p * 256 + tid) * 8;
            int m = idx >> 5, kk = idx & 31;
            int r = row0 + m;
            h8 av = {};
            if (r < NN) av = *(const h8*)&A[(size_t)r * lda + k0 + kk];
            if (XFORM) {
                #pragma unroll
                for (int j = 0; j < 8; ++j) {
                    float a = (float)av[j];
                    a = fmaxf(fmaf(a, SS[k0 + kk + j], SS[K + k0 + kk + j]), 0.0f);
                    av[j] = (_Float16)a;
                }
            }
            *(h8*)&As[m][kk] = av;
        }
        {
            int idx = tid * 8;
            int n = idx >> 5, kk = idx & 31;
            h8 bv = *(const h8*)&Wt[(size_t)(col0 + n) * K + k0 + kk];
            *(h8*)&Bs[n][kk] = bv;
        }
        __syncthreads();
        h8 a[4], b[2];
        #pragma unroll
        for (int m = 0; m < 4; ++m)
            a[m] = *(const h8*)&As[wr * 64 + m * 16 + fr][kb];
        #pragma unroll
        for (int n = 0; n < 2; ++n)
            b[n] = *(const h8*)&Bs[wc * 32 + n * 16 + fr][kb];
        #pragma unroll
        for (int m = 0; m < 4; ++m)
            #pragma unroll
            for (int n = 0; n < 2; ++n)
                acc[m][n] = __builtin_amdgcn_mfma_f32_16x16x32_f16(a[m], b[n], acc[m][n], 0, 0, 0);
        __syncthreads();
    }

    const int fq = lane >> 4;
    #pragma unroll
    for (int m = 0; m < 4; ++m) {
        #pragma unroll
        for (int j = 0; j < 4; ++j) {
            int r = row0 + wr * 64 + m * 16 + fq * 4 + j;
            if (r >= NN) continue;
            float dv = EPI_DINV ? dinv[r] : 1.0f;
            #pragma unroll
            for (int n = 0; n < 2; ++n) {
                int c = col0 + wc * 32 + n * 16 + fr;
                if (c < ncolsO) out[(size_t)r * ldo + c] = (_Float16)(acc[m][n][j] * dv);
            }
        }
    }
}

// ---------------- BatchNorm stats (fp16 input, fp32 accumulate) ----------------

__global__ void bn_stats_kernel(const _Float16* __restrict__ h, float* __restrict__ sums) {
    int t = threadIdx.x;
    float s1 = 0.0f, s2 = 0.0f;
    for (int r = blockIdx.x; r < NN; r += gridDim.x) {
        float v = (float)h[(size_t)r * HD + t];
        s1 += v; s2 += v * v;
    }
    atomicAdd(&sums[t], s1);
    atomicAdd(&sums[HD + t], s2);
}

__global__ void bn_finalize_kernel(const float* __restrict__ sums,
                                   const float* __restrict__ g, const float* __restrict__ be,
                                   float* __restrict__ ss) {
    int t = threadIdx.x;
    float mean = sums[t] * (1.0f / NN);
    float var = sums[HD + t] * (1.0f / NN) - mean * mean;
    float sc = g[t] * rsqrtf(var + 1e-5f);
    ss[t] = sc;
    ss[HD + t] = be[t] - mean * sc;
}

// ---------------- launch ----------------

extern "C" void kernel_launch(void* const* d_in, const int* in_sizes, int n_in,
                              void* d_out, int out_size, void* d_ws, size_t ws_size,
                              hipStream_t stream) {
    const float* x   = (const float*)d_in[0];
    const int*   ei  = (const int*)d_in[1];
    const float* W0  = (const float*)d_in[3];
    const float* g0  = (const float*)d_in[5];
    const float* be0 = (const float*)d_in[6];
    const float* W1  = (const float*)d_in[7];
    const float* g1  = (const float*)d_in[9];
    const float* be1 = (const float*)d_in[10];
    const float* W2  = (const float*)d_in[11];
    const float* b2  = (const float*)d_in[12];
    float* out = (float*)d_out;

    const int* src = ei;            // edge_index[0]
    const int* dst = ei + NE;       // edge_index[1]

    // workspace layout
    const size_t S = 51200000;                        // 100000*256*2 bytes
    char* ws = (char*)d_ws;
    _Float16* S1   = (_Float16*)ws;                   // t1 / t2 slot
    _Float16* xh   = S1;                              // [NN][128] fp16
    _Float16* a0   = S1 + 12800000;                   // [NN][128] fp16
    _Float16* S2   = (_Float16*)(ws + S);             // h0 / h1 slot
    char* base2 = ws + 2 * S;
    int*   csr  = (int*)  (base2);                    // 12.8MB
    int*   offs = (int*)  (base2 + 12800000);         // NN+1 ints
    float* dinv = (float*)(base2 + 13200064);
    float* bns  = (float*)(base2 + 13600064);
    float* ssb  = (float*)(base2 + 13602112);
    int*   bsum = (int*)  (base2 + 13604160);         // up to 1025 ints
    _Float16* wt0 = (_Float16*)(base2 + 13608320);    // [256][128]
    _Float16* wt1 = (_Float16*)(base2 + 13673856);    // [256][256]
    _Float16* wt2 = (_Float16*)(base2 + 13804928);    // [64][256]
    int*   hist = (int*)  (base2 + 13837696);         // NBKT*G+1 ints
    int*   epk  = (int*)  (base2 + 14640576);         // NE ints = 12.8MB

    // CSR build: bucketed counting sort (no HBM write amplification)
    const int N2 = NBKT * G;                // 200704
    const int NB2 = (N2 + 255) / 256;       // 784
    hist_kernel<<<G, 256, 0, stream>>>(dst, hist);
    scan1_kernel<<<NB2, 256, 0, stream>>>(hist, hist, bsum, N2);
    scan2_kernel<<<1, 1024, 0, stream>>>(bsum, NB2);
    scan3_kernel<<<NB2, 256, 0, stream>>>(hist, bsum, NB2, N2);
    scatter_kernel<<<G, 256, 0, stream>>>(src, dst, hist, epk);
    bucket_fill_kernel<<<NBKT, 256, 0, stream>>>(hist, epk, csr, offs, dinv);

    // weights -> fp16 transposed
    wtrans_kernel<FIN><<<(256 * FIN + 255) / 256, 256, 0, stream>>>(W0, wt0, HD, HD);
    wtrans_kernel<HD><<<(256 * HD + 255) / 256, 256, 0, stream>>>(W1, wt1, HD, HD);
    wtrans_kernel<HD><<<(COP * HD + 255) / 256, 256, 0, stream>>>(W2, wt2, CO, COP);

    const int MB = (NN + 127) / 128;   // 782

    // Layer 0 (reassociated): a0 = D^-1/2 (A+I) D^-1/2 x; h0 = a0 @ W0
    conv_x_kernel<<<(NN * FIN / 4 + 255) / 256, 256, 0, stream>>>(x, dinv, xh);
    agg128_kernel<<<NN / 4, 256, 0, stream>>>(xh, offs, csr, dinv, a0);
    mfma_gemm_kernel<FIN, false, false><<<dim3(MB, 4), 256, 0, stream>>>(
        a0, FIN, wt0, nullptr, dinv, S2, HD, HD);               // h0 -> S2

    hipMemsetAsync(bns, 0, 2 * HD * sizeof(float), stream);
    bn_stats_kernel<<<1024, 256, 0, stream>>>(S2, bns);
    bn_finalize_kernel<<<1, HD, 0, stream>>>(bns, g0, be0, ssb);

    // Layer 1: t1 = dinv * (relu(bn(h0)) @ W1); h1 = dinv*(A+I)t1
    mfma_gemm_kernel<HD, true, true><<<dim3(MB, 4), 256, 0, stream>>>(
        S2, HD, wt1, ssb, dinv, S1, HD, HD);                    // t1 -> S1
    agg256_kernel<<<NN / 4, 256, 0, stream>>>(S1, offs, csr, dinv, S2);  // h1 -> S2

    hipMemsetAsync(bns, 0, 2 * HD * sizeof(float), stream);
    bn_stats_kernel<<<1024, 256, 0, stream>>>(S2, bns);
    bn_finalize_kernel<<<1, HD, 0, stream>>>(bns, g1, be1, ssb);

    // Layer 2: t2 = dinv * (relu(bn(h1)) @ W2), rows padded to 64; agg + log_softmax
    mfma_gemm_kernel<HD, true, true><<<dim3(MB, 1), 256, 0, stream>>>(
        S2, HD, wt2, ssb, dinv, S1, COP, COP);                  // t2 -> S1
    agg47_lsm_kernel<<<NN / 4, 256, 0, stream>>>(S1, offs, csr, dinv, b2, out);
}

// Round 6
// 719.292 us; speedup vs baseline: 3.1367x; 1.0348x over previous
//
#include <hip/hip_runtime.h>
#include <hip/hip_fp8.h>
#include <math.h>

#define NN 100000
#define NE 3200000
#define FIN 128
#define HD 256
#define CO 47
#define COP 64     // padded row for layer-2 gather (one 128B line)
#define NBKT 196   // buckets of 512 nodes: dst>>9
#define G 1024     // partition blocks
#define CHUNK 3125 // NE / G exactly

typedef _Float16 h2 __attribute__((ext_vector_type(2)));
typedef _Float16 h4 __attribute__((ext_vector_type(4)));
typedef _Float16 h8 __attribute__((ext_vector_type(8)));
typedef float f32x4 __attribute__((ext_vector_type(4)));

// ---------------- CSR build via bucketed counting sort ----------------

__global__ __launch_bounds__(256) void hist_kernel(const int* __restrict__ dst,
                                                   int* __restrict__ hist) {
    __shared__ int h[NBKT];
    int tid = threadIdx.x;
    for (int i = tid; i < NBKT; i += 256) h[i] = 0;
    __syncthreads();
    int base = blockIdx.x * CHUNK;
    for (int i = tid; i < CHUNK; i += 256)
        atomicAdd(&h[dst[base + i] >> 9], 1);
    __syncthreads();
    for (int i = tid; i < NBKT; i += 256) hist[i * G + blockIdx.x] = h[i];
}

__global__ void scan1_kernel(const int* __restrict__ in, int* __restrict__ out,
                             int* __restrict__ bsum, int n) {
    __shared__ int tmp[256];
    int t = threadIdx.x;
    int i = blockIdx.x * 256 + t;
    int v = (i < n) ? in[i] : 0;
    tmp[t] = v;
    __syncthreads();
    #pragma unroll
    for (int off = 1; off < 256; off <<= 1) {
        int u = (t >= off) ? tmp[t - off] : 0;
        __syncthreads();
        tmp[t] += u;
        __syncthreads();
    }
    if (i < n) out[i] = tmp[t] - v;
    if (t == 255) bsum[blockIdx.x] = tmp[255];
}

__global__ void scan2_kernel(int* __restrict__ bsum, int nb) {
    __shared__ int tmp[1024];
    int t = threadIdx.x;
    int v = (t < nb) ? bsum[t] : 0;
    tmp[t] = v;
    __syncthreads();
    #pragma unroll
    for (int off = 1; off < 1024; off <<= 1) {
        int u = (t >= off) ? tmp[t - off] : 0;
        __syncthreads();
        tmp[t] += u;
        __syncthreads();
    }
    if (t < nb) bsum[t] = tmp[t] - v;
    if (t == nb - 1) bsum[nb] = tmp[t];
}

__global__ void scan3_kernel(int* __restrict__ out, const int* __restrict__ bsum,
                             int nb, int n) {
    int i = blockIdx.x * 256 + threadIdx.x;
    if (i < n) out[i] += bsum[i >> 8];
    if (i == 0) out[n] = bsum[nb];
}

__global__ __launch_bounds__(256) void scatter_kernel(const int* __restrict__ src,
                                                      const int* __restrict__ dst,
                                                      const int* __restrict__ hscan,
                                                      int* __restrict__ epk) {
    __shared__ int cur[NBKT];
    int tid = threadIdx.x;
    for (int i = tid; i < NBKT; i += 256) cur[i] = hscan[i * G + blockIdx.x];
    __syncthreads();
    int base = blockIdx.x * CHUNK;
    for (int i = tid; i < CHUNK; i += 256) {
        int e = base + i;
        int d = dst[e];
        int slot = atomicAdd(&cur[d >> 9], 1);
        epk[slot] = ((d & 511) << 17) | src[e];
    }
}

__global__ __launch_bounds__(256) void bucket_fill_kernel(
    const int* __restrict__ hscan, const int* __restrict__ epk,
    int* __restrict__ csr, int* __restrict__ offs, float* __restrict__ dinv)
{
    __shared__ int deg[512], cur[512], a0[512], a1[512];
    int tid = threadIdx.x, b = blockIdx.x;
    int ebeg = hscan[b * G], eend = hscan[(b + 1) * G];
    deg[tid] = 0; deg[tid + 256] = 0;
    __syncthreads();
    for (int e = ebeg + tid; e < eend; e += 256)
        atomicAdd(&deg[((unsigned)epk[e]) >> 17], 1);
    __syncthreads();
    a0[tid] = deg[tid]; a0[tid + 256] = deg[tid + 256];
    __syncthreads();
    int* pin = a0; int* pout = a1;
    for (int off = 1; off < 512; off <<= 1) {
        #pragma unroll
        for (int q = 0; q < 2; ++q) {
            int p = tid + q * 256;
            pout[p] = pin[p] + ((p >= off) ? pin[p - off] : 0);
        }
        __syncthreads();
        int* t = pin; pin = pout; pout = t;
    }
    #pragma unroll
    for (int q = 0; q < 2; ++q) {
        int i = tid + q * 256;
        int excl = pin[i] - deg[i];
        cur[i] = excl;
        int node = b * 512 + i;
        if (node < NN) {
            offs[node] = ebeg + excl;
            dinv[node] = rsqrtf((float)deg[i] + 1.0f);
        }
    }
    if (b == 0 && tid == 0) offs[NN] = NE;
    __syncthreads();
    for (int e = ebeg + tid; e < eend; e += 256) {
        int pk = epk[e];
        int p = atomicAdd(&cur[((unsigned)pk) >> 17], 1);
        csr[ebeg + p] = pk & 0x1FFFF;
    }
}

// ---------------- weight convert ----------------

template<int K>
__global__ void wtrans_kernel(const float* __restrict__ W, _Float16* __restrict__ Wt,
                              int N, int NP) {
    int i = blockIdx.x * 256 + threadIdx.x;
    if (i >= NP * K) return;
    int n = i / K, k = i % K;
    float v = (n < N) ? W[(size_t)k * N + n] : 0.0f;
    Wt[i] = (_Float16)v;
}

// ---------------- x -> fp8 e4m3 (OCP), pre-scaled by dinv ----------------

__global__ void conv_x_kernel(const float* __restrict__ x, const float* __restrict__ dinv,
                              unsigned* __restrict__ xq) {
    int i = blockIdx.x * 256 + threadIdx.x;     // over NN*FIN/4
    if (i >= NN * FIN / 4) return;
    int r = i >> 5;
    float4 v = ((const float4*)x)[i];
    float dv = dinv[r];
    __hip_fp8_e4m3 q0(v.x * dv), q1(v.y * dv), q2(v.z * dv), q3(v.w * dv);
    unsigned u = (unsigned)q0.__x | ((unsigned)q1.__x << 8) |
                 ((unsigned)q2.__x << 16) | ((unsigned)q3.__x << 24);
    xq[i] = u;
}

// decode OCP e4m3fn -> float (exact, incl. subnormals): fp16(bits=(u&0x7f)<<7) * 256
__device__ inline float dec8(unsigned u) {
    unsigned short hb = (unsigned short)((u & 0x7Fu) << 7);
    float f = (float)__builtin_bit_cast(_Float16, hb) * 256.0f;
    unsigned fb = __builtin_bit_cast(unsigned, f) ^ ((u & 0x80u) << 24);
    return __builtin_bit_cast(float, fb);
}

// ---------------- aggregation (wave per node, atomic-free) ----------------

__global__ __launch_bounds__(256) void agg128_kernel(
    const unsigned short* __restrict__ xq, const int* __restrict__ offs,
    const int* __restrict__ csr, const float* __restrict__ dinv,
    _Float16* __restrict__ out)
{
    int lane = threadIdx.x & 63;
    int v = blockIdx.x * 4 + (threadIdx.x >> 6);
    unsigned sv = xq[(size_t)v * 64 + lane];    // 2 fp8 per lane
    float ax = dec8(sv & 0xFF), ay = dec8(sv >> 8);
    int b = offs[v], e = offs[v + 1], j = b;
    int s[8];
    if (j + 8 <= e) {
        #pragma unroll
        for (int q = 0; q < 8; ++q) s[q] = csr[j + q];
    }
    for (; j + 8 <= e; ) {
        int nj = j + 8;
        int ns[8];
        if (nj + 8 <= e) {
            #pragma unroll
            for (int q = 0; q < 8; ++q) ns[q] = csr[nj + q];
        }
        #pragma unroll
        for (int q = 0; q < 8; ++q) {
            unsigned t = xq[(size_t)s[q] * 64 + lane];
            ax += dec8(t & 0xFF); ay += dec8(t >> 8);
        }
        #pragma unroll
        for (int q = 0; q < 8; ++q) s[q] = ns[q];
        j = nj;
    }
    for (; j < e; ++j) {
        unsigned t = xq[(size_t)csr[j] * 64 + lane];
        ax += dec8(t & 0xFF); ay += dec8(t >> 8);
    }
    float dv = dinv[v];
    h2 o; o[0] = (_Float16)(ax * dv); o[1] = (_Float16)(ay * dv);
    ((h2*)out)[(size_t)v * 64 + lane] = o;
}

__global__ __launch_bounds__(256) void agg256_kernel(
    const _Float16* __restrict__ hp, const int* __restrict__ offs,
    const int* __restrict__ csr, const float* __restrict__ dinv,
    _Float16* __restrict__ out)
{
    int lane = threadIdx.x & 63;
    int v = blockIdx.x * 4 + (threadIdx.x >> 6);
    const h4* rows = (const h4*)hp;
    h4 sv = rows[(size_t)v * 64 + lane];
    float a0 = (float)sv[0], a1 = (float)sv[1], a2 = (float)sv[2], a3 = (float)sv[3];
    int b = offs[v], e = offs[v + 1], j = b;
    int s[8];
    if (j + 8 <= e) {
        #pragma unroll
        for (int q = 0; q < 8; ++q) s[q] = csr[j + q];
    }
    for (; j + 8 <= e; ) {
        int nj = j + 8;
        int ns[8];
        if (nj + 8 <= e) {
            #pragma unroll
            for (int q = 0; q < 8; ++q) ns[q] = csr[nj + q];
        }
        #pragma unroll
        for (int q = 0; q < 8; ++q) {
            h4 t = rows[(size_t)s[q] * 64 + lane];
            a0 += (float)t[0]; a1 += (float)t[1]; a2 += (float)t[2]; a3 += (float)t[3];
        }
        #pragma unroll
        for (int q = 0; q < 8; ++q) s[q] = ns[q];
        j = nj;
    }
    for (; j < e; ++j) {
        h4 t = rows[(size_t)csr[j] * 64 + lane];
        a0 += (float)t[0]; a1 += (float)t[1]; a2 += (float)t[2]; a3 += (float)t[3];
    }
    float dv = dinv[v];
    h4 o; o[0] = (_Float16)(a0 * dv); o[1] = (_Float16)(a1 * dv);
    o[2] = (_Float16)(a2 * dv); o[3] = (_Float16)(a3 * dv);
    ((h4*)out)[(size_t)v * 64 + lane] = o;
}

__global__ __launch_bounds__(256) void agg47_lsm_kernel(
    const _Float16* __restrict__ t2, const int* __restrict__ offs,
    const int* __restrict__ csr, const float* __restrict__ dinv,
    const float* __restrict__ bias, float* __restrict__ out)
{
    int lane = threadIdx.x & 63;
    int v = blockIdx.x * 4 + (threadIdx.x >> 6);
    float acc = (float)t2[(size_t)v * COP + lane];
    int b = offs[v], e = offs[v + 1], j = b;
    int s[8];
    if (j + 8 <= e) {
        #pragma unroll
        for (int q = 0; q < 8; ++q) s[q] = csr[j + q];
    }
    for (; j + 8 <= e; ) {
        int nj = j + 8;
        int ns[8];
        if (nj + 8 <= e) {
            #pragma unroll
            for (int q = 0; q < 8; ++q) ns[q] = csr[nj + q];
        }
        #pragma unroll
        for (int q = 0; q < 8; ++q) acc += (float)t2[(size_t)s[q] * COP + lane];
        #pragma unroll
        for (int q = 0; q < 8; ++q) s[q] = ns[q];
        j = nj;
    }
    for (; j < e; ++j) acc += (float)t2[(size_t)csr[j] * COP + lane];
    bool act = lane < CO;
    float val = act ? fmaf(acc, dinv[v], bias[lane]) : -1e30f;
    float m = val;
    #pragma unroll
    for (int o = 32; o > 0; o >>= 1) m = fmaxf(m, __shfl_xor(m, o, 64));
    float ex = act ? expf(val - m) : 0.0f;
    float sum = ex;
    #pragma unroll
    for (int o = 32; o > 0; o >>= 1) sum += __shfl_xor(sum, o, 64);
    if (act) out[(size_t)v * CO + lane] = val - m - logf(sum);
}

// ---------------- big MFMA GEMM: BM=128, BN=128, BK=64, 4 waves (2x2), 64x64/wave ----

#define LDS_PAD 8

template<int K, bool XFORM, bool EPI_DINV>
__global__ __launch_bounds__(256) void mfma_gemm_big(
    const _Float16* __restrict__ A, int lda,
    const _Float16* __restrict__ Wt,
    const float* __restrict__ ss, const float* __restrict__ dinv,
    _Float16* __restrict__ out, int ldo)
{
    __shared__ __align__(16) _Float16 As[128][64 + LDS_PAD];
    __shared__ __align__(16) _Float16 Bs[128][64 + LDS_PAD];
    __shared__ float SS[2 * K];
    const int row0 = blockIdx.x * 128;
    const int col0 = blockIdx.y * 128;
    const int tid = threadIdx.x;
    if (XFORM) {
        for (int i = tid; i < 2 * K; i += 256) SS[i] = ss[i];
    }
    const int lane = tid & 63;
    const int wv = tid >> 6;
    const int wr = wv >> 1, wc = wv & 1;
    const int fr = lane & 15;
    const int kb = (lane >> 4) * 8;

    f32x4 acc[4][4];
    #pragma unroll
    for (int m = 0; m < 4; ++m)
        #pragma unroll
        for (int n = 0; n < 4; ++n)
            acc[m][n] = (f32x4){0.f, 0.f, 0.f, 0.f};

    if (XFORM) __syncthreads();

    for (int k0 = 0; k0 < K; k0 += 64) {
        // stage A: 128x64 halves, 4 chunks of h8 per thread
        #pragma unroll
        for (int p = 0; p < 4; ++p) {
            int c = p * 256 + tid;
            int m = c >> 3, kk = (c & 7) * 8;
            int r = row0 + m;
            h8 av = {};
            if (r < NN) av = *(const h8*)&A[(size_t)r * lda + k0 + kk];
            if (XFORM) {
                #pragma unroll
                for (int j = 0; j < 8; ++j) {
                    float a = (float)av[j];
                    a = fmaxf(fmaf(a, SS[k0 + kk + j], SS[K + k0 + kk + j]), 0.0f);
                    av[j] = (_Float16)a;
                }
            }
            *(h8*)&As[m][kk] = av;
        }
        // stage B: 128x64 halves
        #pragma unroll
        for (int p = 0; p < 4; ++p) {
            int c = p * 256 + tid;
            int n = c >> 3, kk = (c & 7) * 8;
            h8 bv = *(const h8*)&Wt[(size_t)(col0 + n) * K + k0 + kk];
            *(h8*)&Bs[n][kk] = bv;
        }
        __syncthreads();
        #pragma unroll
        for (int ks = 0; ks < 2; ++ks) {
            h8 a[4], b[4];
            #pragma unroll
            for (int m = 0; m < 4; ++m)
                a[m] = *(const h8*)&As[wr * 64 + m * 16 + fr][ks * 32 + kb];
            #pragma unroll
            for (int n = 0; n < 4; ++n)
                b[n] = *(const h8*)&Bs[wc * 64 + n * 16 + fr][ks * 32 + kb];
            #pragma unroll
            for (int m = 0; m < 4; ++m)
                #pragma unroll
                for (int n = 0; n < 4; ++n)
                    acc[m][n] = __builtin_amdgcn_mfma_f32_16x16x32_f16(a[m], b[n], acc[m][n], 0, 0, 0);
        }
        __syncthreads();
    }

    const int fq = lane >> 4;
    #pragma unroll
    for (int m = 0; m < 4; ++m) {
        #pragma unroll
        for (int j = 0; j < 4; ++j) {
            int r = row0 + wr * 64 + m * 16 + fq * 4 + j;
            if (r >= NN) continue;
            float dv = EPI_DINV ? dinv[r] : 1.0f;
            #pragma unroll
            for (int n = 0; n < 4; ++n) {
                int c = col0 + wc * 64 + n * 16 + fr;
                out[(size_t)r * ldo + c] = (_Float16)(acc[m][n][j] * dv);
            }
        }
    }
}

// ---------------- narrow MFMA GEMM for layer 2 (BN=64), as before ----------------

template<int K, bool XFORM, bool EPI_DINV>
__global__ __launch_bounds__(256) void mfma_gemm_kernel(
    const _Float16* __restrict__ A, int lda,
    const _Float16* __restrict__ Wt,
    const float* __restrict__ ss, const float* __restrict__ dinv,
    _Float16* __restrict__ out, int ldo, int ncolsO)
{
    __shared__ __align__(16) _Float16 As[128][32 + LDS_PAD];
    __shared__ __align__(16) _Float16 Bs[64][32 + LDS_PAD];
    __shared__ float SS[2 * K];
    const int row0 = blockIdx.x * 128;
    const int col0 = blockIdx.y * 64;
    const int tid = threadIdx.x;
    if (XFORM) {
        for (int i = tid; i < 2 * K; i += 256) SS[i] = ss[i];
    }
    const int lane = tid & 63;
    const int wv = tid >> 6;
    const int wr = wv >> 1, wc = wv & 1;
    const int fr = lane & 15;
    const int kb = (lane >> 4) * 8;

    f32x4 acc[4][2];
    #pragma unroll
    for (int m = 0; m < 4; ++m)
        #pragma unroll
        for (int n = 0; n < 2; ++n)
            acc[m][n] = (f32x4){0.f, 0.f, 0.f, 0.f};

    if (XFORM) __syncthreads();

    for (int k0 = 0; k0 < K; k0 += 32) {
        #pragma unroll
        for (int p = 0; p < 2; ++p) {
            int idx = (p * 256 + tid) * 8;
            int m = idx >> 5, kk = idx & 31;
            int r = row0 + m;
            h8 av = {};
            if (r < NN) av = *(const h8*)&A[(size_t)r * lda + k0 + kk];
            if (XFORM) {
                #pragma unroll
                for (int j = 0; j < 8; ++j) {
                    float a = (float)av[j];
                    a = fmaxf(fmaf(a, SS[k0 + kk + j], SS[K + k0 + kk + j]), 0.0f);
                    av[j] = (_Float16)a;
                }
            }
            *(h8*)&As[m][kk] = av;
        }
        {
            int idx = tid * 8;
            int n = idx >> 5, kk = idx & 31;
            h8 bv = *(const h8*)&Wt[(size_t)(col0 + n) * K + k0 + kk];
            *(h8*)&Bs[n][kk] = bv;
        }
        __syncthreads();
        h8 a[4], b[2];
        #pragma unroll
        for (int m = 0; m < 4; ++m)
            a[m] = *(const h8*)&As[wr * 64 + m * 16 + fr][kb];
        #pragma unroll
        for (int n = 0; n < 2; ++n)
            b[n] = *(const h8*)&Bs[wc * 32 + n * 16 + fr][kb];
        #pragma unroll
        for (int m = 0; m < 4; ++m)
            #pragma unroll
            for (int n = 0; n < 2; ++n)
                acc[m][n] = __builtin_amdgcn_mfma_f32_16x16x32_f16(a[m], b[n], acc[m][n], 0, 0, 0);
        __syncthreads();
    }

    const int fq = lane >> 4;
    #pragma unroll
    for (int m = 0; m < 4; ++m) {
        #pragma unroll
        for (int j = 0; j < 4; ++j) {
            int r = row0 + wr * 64 + m * 16 + fq * 4 + j;
            if (r >= NN) continue;
            float dv = EPI_DINV ? dinv[r] : 1.0f;
            #pragma unroll
            for (int n = 0; n < 2; ++n) {
                int c = col0 + wc * 32 + n * 16 + fr;
                if (c < ncolsO) out[(size_t)r * ldo + c] = (_Float16)(acc[m][n][j] * dv);
            }
        }
    }
}

// ---------------- BatchNorm stats: vectorized partials + fused reduce/finalize ----

__global__ __launch_bounds__(256) void bn_part_kernel(const _Float16* __restrict__ h,
                                                      float* __restrict__ part) {
    int tid = threadIdx.x;
    int fg = tid & 63;          // feature group of 4
    int rg = tid >> 6;          // row group 0..3
    float s1[4] = {}, s2[4] = {};
    for (int r = blockIdx.x * 4 + rg; r < NN; r += 4096) {
        h4 v = ((const h4*)(h + (size_t)r * HD))[fg];
        #pragma unroll
        for (int j = 0; j < 4; ++j) {
            float f = (float)v[j];
            s1[j] += f; s2[j] += f * f;
        }
    }
    __shared__ float sm[256][8];
    #pragma unroll
    for (int j = 0; j < 4; ++j) { sm[tid][j] = s1[j]; sm[tid][4 + j] = s2[j]; }
    __syncthreads();
    if (tid < 64) {
        float o1[4] = {}, o2[4] = {};
        #pragma unroll
        for (int r = 0; r < 4; ++r)
            #pragma unroll
            for (int j = 0; j < 4; ++j) {
                o1[j] += sm[r * 64 + tid][j];
                o2[j] += sm[r * 64 + tid][4 + j];
            }
        #pragma unroll
        for (int j = 0; j < 4; ++j) {
            part[(size_t)blockIdx.x * 512 + tid * 4 + j] = o1[j];
            part[(size_t)blockIdx.x * 512 + 256 + tid * 4 + j] = o2[j];
        }
    }
}

__global__ __launch_bounds__(256) void bn_reduce_kernel(const float* __restrict__ part,
                                                        const float* __restrict__ g,
                                                        const float* __restrict__ be,
                                                        float* __restrict__ ss) {
    int f = blockIdx.x * 32 + (threadIdx.x & 31);
    int c = threadIdx.x >> 5;   // 0..7
    float s1 = 0.f, s2 = 0.f;
    for (int b = c; b < 1024; b += 8) {
        s1 += part[(size_t)b * 512 + f];
        s2 += part[(size_t)b * 512 + 256 + f];
    }
    __shared__ float m1[8][32], m2[8][32];
    m1[c][threadIdx.x & 31] = s1; m2[c][threadIdx.x & 31] = s2;
    __syncthreads();
    if (threadIdx.x < 32) {
        float t1 = 0.f, t2 = 0.f;
        #pragma unroll
        for (int q = 0; q < 8; ++q) { t1 += m1[q][threadIdx.x]; t2 += m2[q][threadIdx.x]; }
        float mean = t1 * (1.0f / NN);
        float var = t2 * (1.0f / NN) - mean * mean;
        float sc = g[f] * rsqrtf(var + 1e-5f);
        ss[f] = sc;
        ss[HD + f] = be[f] - mean * sc;
    }
}

// ---------------- launch ----------------

extern "C" void kernel_launch(void* const* d_in, const int* in_sizes, int n_in,
                              void* d_out, int out_size, void* d_ws, size_t ws_size,
                              hipStream_t stream) {
    const float* x   = (const float*)d_in[0];
    const int*   ei  = (const int*)d_in[1];
    const float* W0  = (const float*)d_in[3];
    const float* g0  = (const float*)d_in[5];
    const float* be0 = (const float*)d_in[6];
    const float* W1  = (const float*)d_in[7];
    const float* g1  = (const float*)d_in[9];
    const float* be1 = (const float*)d_in[10];
    const float* W2  = (const float*)d_in[11];
    const float* b2  = (const float*)d_in[12];
    float* out = (float*)d_out;

    const int* src = ei;            // edge_index[0]
    const int* dst = ei + NE;       // edge_index[1]

    const size_t S = 51200000;                        // 100000*256*2 bytes
    char* ws = (char*)d_ws;
    _Float16* S1   = (_Float16*)ws;                   // t1 / t2 slot
    unsigned* xq   = (unsigned*)ws;                   // [NN][128] fp8 (12.8MB)
    _Float16* a0   = (_Float16*)(ws + 12800000);      // [NN][128] fp16 (25.6MB)
    _Float16* S2   = (_Float16*)(ws + S);             // h0 / h1 slot
    char* base2 = ws + 2 * S;
    int*   csr  = (int*)  (base2);                    // 12.8MB
    int*   offs = (int*)  (base2 + 12800000);
    float* dinv = (float*)(base2 + 13200064);
    float* ssb  = (float*)(base2 + 13602112);
    int*   bsum = (int*)  (base2 + 13604160);
    _Float16* wt0 = (_Float16*)(base2 + 13608320);    // [256][128]
    _Float16* wt1 = (_Float16*)(base2 + 13673856);    // [256][256]
    _Float16* wt2 = (_Float16*)(base2 + 13804928);    // [64][256]
    int*   hist = (int*)  (base2 + 13837696);         // NBKT*G+1 ints
    int*   epk  = (int*)  (base2 + 14640576);         // NE ints = 12.8MB
    float* part = (float*)(base2 + 27440576);         // 1024*512 floats = 2MB

    // CSR build: bucketed counting sort
    const int N2 = NBKT * G;
    const int NB2 = (N2 + 255) / 256;
    hist_kernel<<<G, 256, 0, stream>>>(dst, hist);
    scan1_kernel<<<NB2, 256, 0, stream>>>(hist, hist, bsum, N2);
    scan2_kernel<<<1, 1024, 0, stream>>>(bsum, NB2);
    scan3_kernel<<<NB2, 256, 0, stream>>>(hist, bsum, NB2, N2);
    scatter_kernel<<<G, 256, 0, stream>>>(src, dst, hist, epk);
    bucket_fill_kernel<<<NBKT, 256, 0, stream>>>(hist, epk, csr, offs, dinv);

    // weights -> fp16 transposed
    wtrans_kernel<FIN><<<(256 * FIN + 255) / 256, 256, 0, stream>>>(W0, wt0, HD, HD);
    wtrans_kernel<HD><<<(256 * HD + 255) / 256, 256, 0, stream>>>(W1, wt1, HD, HD);
    wtrans_kernel<HD><<<(COP * HD + 255) / 256, 256, 0, stream>>>(W2, wt2, CO, COP);

    const int MB = (NN + 127) / 128;   // 782

    // Layer 0 (reassociated): a0 = D^-1/2 (A+I) D^-1/2 x (fp8 gather); h0 = a0 @ W0
    conv_x_kernel<<<(NN * FIN / 4 + 255) / 256, 256, 0, stream>>>(x, dinv, xq);
    agg128_kernel<<<NN / 4, 256, 0, stream>>>((const unsigned short*)xq, offs, csr, dinv, a0);
    mfma_gemm_big<FIN, false, false><<<dim3(MB, 2), 256, 0, stream>>>(
        a0, FIN, wt0, nullptr, dinv, S2, HD);                   // h0 -> S2

    bn_part_kernel<<<1024, 256, 0, stream>>>(S2, part);
    bn_reduce_kernel<<<8, 256, 0, stream>>>(part, g0, be0, ssb);

    // Layer 1: t1 = dinv * (relu(bn(h0)) @ W1); h1 = dinv*(A+I)t1
    mfma_gemm_big<HD, true, true><<<dim3(MB, 2), 256, 0, stream>>>(
        S2, HD, wt1, ssb, dinv, S1, HD);                        // t1 -> S1
    agg256_kernel<<<NN / 4, 256, 0, stream>>>(S1, offs, csr, dinv, S2);  // h1 -> S2

    bn_part_kernel<<<1024, 256, 0, stream>>>(S2, part);
    bn_reduce_kernel<<<8, 256, 0, stream>>>(part, g1, be1, ssb);

    // Layer 2: t2 = dinv * (relu(bn(h1)) @ W2), rows padded to 64; agg + log_softmax
    mfma_gemm_kernel<HD, true, true><<<dim3(MB, 1), 256, 0, stream>>>(
        S2, HD, wt2, ssb, dinv, S1, COP, COP);                  // t2 -> S1
    agg47_lsm_kernel<<<NN / 4, 256, 0, stream>>>(S1, offs, csr, dinv, b2, out);
}